// Round 3
// baseline (695.378 us; speedup 1.0000x reference)
//
#include <hip/hip_runtime.h>
#include <hip/hip_bf16.h>

typedef unsigned short u16;
typedef __bf16 v8bf __attribute__((ext_vector_type(8)));
typedef float v4f __attribute__((ext_vector_type(4)));

#define B_SZ 8
#define S_LEN 1024
#define IN_DIM 256
#define DMODEL 512
#define NHEAD 8
#define DK 64
#define FF_DIM 2048
#define MROWS (B_SZ * S_LEN)   // 8192

__device__ __forceinline__ u16 f2bf(float f) {
    unsigned int x = __float_as_uint(f);
    unsigned int r = (x + 0x7fffu + ((x >> 16) & 1u)) >> 16;
    return (u16)r;
}

// ---------------- elementwise f32 -> bf16 (inputs matrix) ----------------
__global__ __launch_bounds__(256) void conv_bf16_kernel(const float* __restrict__ in,
                                                        u16* __restrict__ out, int n4) {
    int i = blockIdx.x * 256 + threadIdx.x;
    if (i < n4) {
        float4 v = ((const float4*)in)[i];
        ushort4 o;
        o.x = f2bf(v.x); o.y = f2bf(v.y); o.z = f2bf(v.z); o.w = f2bf(v.w);
        ((ushort4*)out)[i] = o;
    }
}

// ------------- batched transpose+convert: (K,N) f32 -> (N,K) bf16 -------------
struct TDesc { const float* src; u16* dst; int K; int N; };
struct TArgs { TDesc d[13]; };

__global__ void transpose_conv_kernel(TArgs args) {
    TDesc t = args.d[blockIdx.z];
    int k0 = blockIdx.x * 32, n0 = blockIdx.y * 32;
    if (k0 >= t.K || n0 >= t.N) return;
    __shared__ float tile[32][33];
    int tx = threadIdx.x, ty = threadIdx.y;
#pragma unroll
    for (int j = 0; j < 4; j++) {
        int k = k0 + ty + j * 8;
        tile[ty + j * 8][tx] = t.src[(size_t)k * t.N + n0 + tx];
    }
    __syncthreads();
#pragma unroll
    for (int j = 0; j < 4; j++) {
        int n = n0 + ty + j * 8;
        t.dst[(size_t)n * t.K + k0 + tx] = f2bf(tile[tx][ty + j * 8]);
    }
}

// ---------------- LayerNorm: fp32 in -> bf16 (or fp32) out ----------------
template <bool OUT_BF16>
__global__ __launch_bounds__(256) void ln_kernel(const float* __restrict__ x,
                                                 const float* __restrict__ g,
                                                 const float* __restrict__ b,
                                                 void* __restrict__ out) {
    int row = blockIdx.x * 4 + (threadIdx.x >> 6);
    int lane = threadIdx.x & 63;
    const float4* xr = (const float4*)(x + (size_t)row * DMODEL);
    float4 v0 = xr[lane], v1 = xr[lane + 64];
    float s = v0.x + v0.y + v0.z + v0.w + v1.x + v1.y + v1.z + v1.w;
    float sq = v0.x * v0.x + v0.y * v0.y + v0.z * v0.z + v0.w * v0.w +
               v1.x * v1.x + v1.y * v1.y + v1.z * v1.z + v1.w * v1.w;
#pragma unroll
    for (int m = 1; m < 64; m <<= 1) {
        s += __shfl_xor(s, m);
        sq += __shfl_xor(sq, m);
    }
    float mean = s * (1.0f / DMODEL);
    float var = sq * (1.0f / DMODEL) - mean * mean;
    float rstd = rsqrtf(var + 1e-5f);
    const float4* g4 = (const float4*)g;
    const float4* b4 = (const float4*)b;
    float4 ga = g4[lane], gb = g4[lane + 64], ba = b4[lane], bb = b4[lane + 64];
    float4 r0, r1;
    r0.x = (v0.x - mean) * rstd * ga.x + ba.x;
    r0.y = (v0.y - mean) * rstd * ga.y + ba.y;
    r0.z = (v0.z - mean) * rstd * ga.z + ba.z;
    r0.w = (v0.w - mean) * rstd * ga.w + ba.w;
    r1.x = (v1.x - mean) * rstd * gb.x + bb.x;
    r1.y = (v1.y - mean) * rstd * gb.y + bb.y;
    r1.z = (v1.z - mean) * rstd * gb.z + bb.z;
    r1.w = (v1.w - mean) * rstd * gb.w + bb.w;
    if (OUT_BF16) {
        ushort4 o0, o1;
        o0.x = f2bf(r0.x); o0.y = f2bf(r0.y); o0.z = f2bf(r0.z); o0.w = f2bf(r0.w);
        o1.x = f2bf(r1.x); o1.y = f2bf(r1.y); o1.z = f2bf(r1.z); o1.w = f2bf(r1.w);
        ((ushort4*)out)[(size_t)row * 128 + lane] = o0;
        ((ushort4*)out)[(size_t)row * 128 + 64 + lane] = o1;
    } else {
        ((float4*)out)[(size_t)row * 128 + lane] = r0;
        ((float4*)out)[(size_t)row * 128 + 64 + lane] = r1;
    }
}

// ---------------- bf16 MFMA GEMM (128x128 tile):  Out = A(MxK) @ Bt(NxK)^T + bias ----
// MODE 1: fp32 out (+bias +sinusoid PE)         [input projection]
// MODE 2: bf16 out (+bias, ReLU)                [FFN1]
// MODE 3: fp32 out (+bias + residual R)         [O-proj, FFN2]
// MODE 4: bf16 out (+bias)                      [K projection]
// MODE 5: bf16 out (+bias), transposed [b,col,s] store  [V projection]
// MODE 6: bf16 out ((+bias) * qk-scale)         [Q projection]
#define QSCALE 0.1803368801111204f   // 0.125 * log2(e)
template <int MODE>
__global__ __launch_bounds__(256) void gemm_kernel(const u16* __restrict__ A,
                                                   const u16* __restrict__ Bt,
                                                   const float* __restrict__ bias,
                                                   const float* __restrict__ R,
                                                   void* __restrict__ Out,
                                                   int M, int N, int K) {
    constexpr int LDK = 40;  // u16 elements; 80B row stride -> conflict-free b128 reads
    __shared__ u16 As[128 * LDK];
    __shared__ u16 Bs[128 * LDK];
    int tid = threadIdx.x;
    int n0 = blockIdx.x * 128, m0 = blockIdx.y * 128;
    int w = tid >> 6, lane = tid & 63;
    int wr = (w >> 1) * 64, wc = (w & 1) * 64;
    int lr = lane & 15, lq = lane >> 4;

    v4f zero = {0.f, 0.f, 0.f, 0.f};
    v4f acc[4][4];
#pragma unroll
    for (int i = 0; i < 4; i++)
#pragma unroll
        for (int j = 0; j < 4; j++) acc[i][j] = zero;

    int srow = tid >> 2, scol = (tid & 3) * 8;
    const u16* Aptr = A + (size_t)(m0 + srow) * K + scol;
    const u16* Bptr = Bt + (size_t)(n0 + srow) * K + scol;
    size_t rstep = (size_t)64 * K;
    u16* AsW = &As[srow * LDK + scol];
    u16* BsW = &Bs[srow * LDK + scol];

    for (int k0 = 0; k0 < K; k0 += 32) {
        v8bf a0 = *(const v8bf*)Aptr;
        v8bf a1 = *(const v8bf*)(Aptr + rstep);
        v8bf b0 = *(const v8bf*)Bptr;
        v8bf b1 = *(const v8bf*)(Bptr + rstep);
        __syncthreads();
        *(v8bf*)AsW = a0;
        *(v8bf*)(AsW + 64 * LDK) = a1;
        *(v8bf*)BsW = b0;
        *(v8bf*)(BsW + 64 * LDK) = b1;
        __syncthreads();
        v8bf af[4], bfr[4];
#pragma unroll
        for (int i = 0; i < 4; i++) {
            af[i] = *(const v8bf*)&As[(wr + i * 16 + lr) * LDK + lq * 8];
            bfr[i] = *(const v8bf*)&Bs[(wc + i * 16 + lr) * LDK + lq * 8];
        }
#pragma unroll
        for (int mt = 0; mt < 4; mt++)
#pragma unroll
            for (int nt = 0; nt < 4; nt++)
                acc[mt][nt] = __builtin_amdgcn_mfma_f32_16x16x32_bf16(af[mt], bfr[nt], acc[mt][nt], 0, 0, 0);
        Aptr += 32;
        Bptr += 32;
    }

#pragma unroll
    for (int mt = 0; mt < 4; mt++) {
#pragma unroll
        for (int nt = 0; nt < 4; nt++) {
            int col = n0 + wc + nt * 16 + lr;
            float bcol = bias[col];
            if (MODE == 5) {
                int row0 = m0 + wr + mt * 16 + lq * 4;
                int bb = row0 >> 10, s0 = row0 & (S_LEN - 1);
                ushort4 o;
                o.x = f2bf(acc[mt][nt][0] + bcol);
                o.y = f2bf(acc[mt][nt][1] + bcol);
                o.z = f2bf(acc[mt][nt][2] + bcol);
                o.w = f2bf(acc[mt][nt][3] + bcol);
                *(ushort4*)((u16*)Out + ((size_t)(bb * 512 + col)) * S_LEN + s0) = o;
            } else {
#pragma unroll
                for (int reg = 0; reg < 4; reg++) {
                    int row = m0 + wr + mt * 16 + lq * 4 + reg;
                    float val = acc[mt][nt][reg] + bcol;
                    if (MODE == 1) {
                        int sPos = row & (S_LEN - 1);
                        float freq = expf((float)(col & ~1) * (-0.017988946039015984f));
                        float ang = (float)sPos * freq;
                        val += (col & 1) ? cosf(ang) : sinf(ang);
                    }
                    if (MODE == 2) val = fmaxf(val, 0.0f);
                    if (MODE == 3) val += R[(size_t)row * N + col];
                    if (MODE == 6) val *= QSCALE;
                    if (MODE == 2 || MODE == 4 || MODE == 6)
                        ((u16*)Out)[(size_t)row * N + col] = f2bf(val);
                    else
                        ((float*)Out)[(size_t)row * N + col] = val;
                }
            }
        }
    }
}

// ---------------- MFMA flash attention (barrier-free K-loop) ----------------
// Q bf16 pre-scaled by 0.125*log2e; K bf16 [B*S][D]; Vt bf16 [(b*512+h*64+d)][s]
// block = 4 waves; wave w owns q rows qt*64+w*16..+16; fixed softmax max (m=0)
#define LDT 72
__global__ __launch_bounds__(256) void fattn_kernel(const u16* __restrict__ Qg,
                                                    const u16* __restrict__ Kg,
                                                    const u16* __restrict__ Vtg,
                                                    const float* __restrict__ rb,
                                                    const int* __restrict__ lengths,
                                                    u16* __restrict__ O) {
    int qt = blockIdx.x, h = blockIdx.y, b = blockIdx.z;
    int tid = threadIdx.x, w = tid >> 6, lane = tid & 63;
    int lr = lane & 15, lq = lane >> 4;
    __shared__ u16 Pw[4][16 * LDT];
    __shared__ float rbs[128];
    int len = lengths[b];
    if (tid < 127) rbs[tid] = rb[h * 127 + tid] * 1.4426950408889634f;  // fold log2(e)
    __syncthreads();

    int qb = qt * 64 + w * 16;
    size_t qgbase = ((size_t)(b * S_LEN + qb + lr)) * DMODEL + h * DK;
    v8bf qa0 = *(const v8bf*)(Qg + qgbase + lq * 8);
    v8bf qa1 = *(const v8bf*)(Qg + qgbase + 32 + lq * 8);

    v4f zero = {0.f, 0.f, 0.f, 0.f};
    v4f Oacc[4];
    Oacc[0] = zero; Oacc[1] = zero; Oacc[2] = zero; Oacc[3] = zero;
    float lsum[4] = {0.f, 0.f, 0.f, 0.f};

    const u16* Kbase = Kg + ((size_t)b * S_LEN) * DMODEL + h * DK;
    const u16* Vbase = Vtg + ((size_t)(b * 512 + h * DK)) * S_LEN;
    u16* P = Pw[w];

    for (int kb0 = 0; kb0 < len; kb0 += 64) {
        // S = Q @ K^T : B-fragments loaded directly from global (contiguous 16B/lane)
        v4f S[4];
#pragma unroll
        for (int nt = 0; nt < 4; nt++) {
            const u16* kr = Kbase + (size_t)(kb0 + nt * 16 + lr) * DMODEL + lq * 8;
            v8bf kb_ = *(const v8bf*)kr;
            v8bf kb1 = *(const v8bf*)(kr + 32);
            v4f s = __builtin_amdgcn_mfma_f32_16x16x32_bf16(qa0, kb_, zero, 0, 0, 0);
            S[nt] = __builtin_amdgcn_mfma_f32_16x16x32_bf16(qa1, kb1, s, 0, 0, 0);
        }

        bool edge = (kb0 + 64 > len);
        int dmin = qb - (kb0 + 63), dmax = qb + 15 - kb0;
        bool perel = !(dmax <= -63 || dmin >= 63);
        float bconst = (dmax <= -63) ? rbs[0] : rbs[126];
#pragma unroll
        for (int nt = 0; nt < 4; nt++) {
            int k = kb0 + nt * 16 + lr;
#pragma unroll
            for (int r = 0; r < 4; r++) {
                float s = S[nt][r];
                if (perel) {
                    int d = qb + lq * 4 + r - k;
                    d = d < -63 ? -63 : (d > 63 ? 63 : d);
                    s += rbs[d + 63];
                } else {
                    s += bconst;
                }
                float p = exp2f(s);
                if (edge && k >= len) p = 0.f;
                lsum[r] += p;
                P[(lq * 4 + r) * LDT + nt * 16 + lr] = f2bf(p);
            }
        }

        // O += P @ V : P via per-wave LDS (C-layout -> A-layout), V direct from global
        v8bf pa0 = *(const v8bf*)&P[lr * LDT + lq * 8];
        v8bf pa1 = *(const v8bf*)&P[lr * LDT + 32 + lq * 8];
#pragma unroll
        for (int nt = 0; nt < 4; nt++) {
            const u16* vr = Vbase + (size_t)(nt * 16 + lr) * S_LEN + kb0 + lq * 8;
            v8bf v0 = *(const v8bf*)vr;
            v8bf v1 = *(const v8bf*)(vr + 32);
            Oacc[nt] = __builtin_amdgcn_mfma_f32_16x16x32_bf16(pa0, v0, Oacc[nt], 0, 0, 0);
            Oacc[nt] = __builtin_amdgcn_mfma_f32_16x16x32_bf16(pa1, v1, Oacc[nt], 0, 0, 0);
        }
    }

    // one-time row-sum reduce across the 16 lanes of each quad
    float inv[4];
#pragma unroll
    for (int r = 0; r < 4; r++) {
        float s = lsum[r];
        s += __shfl_xor(s, 1);
        s += __shfl_xor(s, 2);
        s += __shfl_xor(s, 4);
        s += __shfl_xor(s, 8);
        inv[r] = 1.0f / s;
    }

    size_t obase = ((size_t)(b * S_LEN + qb)) * DMODEL + h * DK;
#pragma unroll
    for (int nt = 0; nt < 4; nt++) {
#pragma unroll
        for (int r = 0; r < 4; r++) {
            O[obase + (size_t)(lq * 4 + r) * DMODEL + nt * 16 + lr] = f2bf(Oacc[nt][r] * inv[r]);
        }
    }
}

extern "C" void kernel_launch(void* const* d_in, const int* in_sizes, int n_in,
                              void* d_out, int out_size, void* d_ws, size_t ws_size,
                              hipStream_t stream) {
    const float* inputs   = (const float*)d_in[0];
    const int*   lengths  = (const int*)d_in[1];
    const float* W_in     = (const float*)d_in[2];
    const float* b_in     = (const float*)d_in[3];
    const float* Wq       = (const float*)d_in[4];
    const float* bq       = (const float*)d_in[5];
    const float* Wk       = (const float*)d_in[6];
    const float* bk       = (const float*)d_in[7];
    const float* Wv       = (const float*)d_in[8];
    const float* bv       = (const float*)d_in[9];
    const float* Wo       = (const float*)d_in[10];
    const float* bo       = (const float*)d_in[11];
    const float* rel_bias = (const float*)d_in[12];
    const float* W1       = (const float*)d_in[13];
    const float* b1       = (const float*)d_in[14];
    const float* W2       = (const float*)d_in[15];
    const float* b2       = (const float*)d_in[16];
    const float* g1       = (const float*)d_in[17];
    const float* be1      = (const float*)d_in[18];
    const float* g2       = (const float*)d_in[19];
    const float* be2      = (const float*)d_in[20];
    const float* gf       = (const float*)d_in[21];
    const float* bef      = (const float*)d_in[22];

    // ---- workspace layout ----
    char* ws = (char*)d_ws;
    float* xbuf = (float*)ws;          ws += (size_t)MROWS * DMODEL * 4;   // residual fp32
    u16* hbuf   = (u16*)ws;            ws += (size_t)MROWS * DMODEL * 2;   // LN output bf16
    u16* aobuf  = (u16*)ws;            ws += (size_t)MROWS * DMODEL * 2;   // attn output bf16
    u16* qbf    = (u16*)ws;                                                // union region (48MB):
    u16* kbf    = qbf + (size_t)MROWS * DMODEL;                            //  q/k bf16 + vt bf16
    u16* vtbf   = kbf + (size_t)MROWS * DMODEL;                            //  OR FFN intermediate
    u16* tbuf   = qbf;                 ws += (size_t)MROWS * DMODEL * 4 * 3;
    u16* inbf   = (u16*)ws;            ws += (size_t)MROWS * IN_DIM * 2;   // bf16 inputs
    u16* wt_in  = (u16*)ws;            ws += (size_t)DMODEL * IN_DIM * 2;
    u16 *wtq[2], *wtk[2], *wtv[2], *wto[2], *wt1[2], *wt2[2];
    for (int l = 0; l < 2; l++) { wtq[l] = (u16*)ws; ws += (size_t)DMODEL * DMODEL * 2; }
    for (int l = 0; l < 2; l++) { wtk[l] = (u16*)ws; ws += (size_t)DMODEL * DMODEL * 2; }
    for (int l = 0; l < 2; l++) { wtv[l] = (u16*)ws; ws += (size_t)DMODEL * DMODEL * 2; }
    for (int l = 0; l < 2; l++) { wto[l] = (u16*)ws; ws += (size_t)DMODEL * DMODEL * 2; }
    for (int l = 0; l < 2; l++) { wt1[l] = (u16*)ws; ws += (size_t)FF_DIM * DMODEL * 2; }
    for (int l = 0; l < 2; l++) { wt2[l] = (u16*)ws; ws += (size_t)DMODEL * FF_DIM * 2; }

    TArgs ta;
    int ti = 0;
    ta.d[ti++] = {W_in, wt_in, IN_DIM, DMODEL};
    for (int l = 0; l < 2; l++) ta.d[ti++] = {Wq + (size_t)l * DMODEL * DMODEL, wtq[l], DMODEL, DMODEL};
    for (int l = 0; l < 2; l++) ta.d[ti++] = {Wk + (size_t)l * DMODEL * DMODEL, wtk[l], DMODEL, DMODEL};
    for (int l = 0; l < 2; l++) ta.d[ti++] = {Wv + (size_t)l * DMODEL * DMODEL, wtv[l], DMODEL, DMODEL};
    for (int l = 0; l < 2; l++) ta.d[ti++] = {Wo + (size_t)l * DMODEL * DMODEL, wto[l], DMODEL, DMODEL};
    for (int l = 0; l < 2; l++) ta.d[ti++] = {W1 + (size_t)l * DMODEL * FF_DIM, wt1[l], DMODEL, FF_DIM};
    for (int l = 0; l < 2; l++) ta.d[ti++] = {W2 + (size_t)l * FF_DIM * DMODEL, wt2[l], FF_DIM, DMODEL};

    conv_bf16_kernel<<<dim3((MROWS * IN_DIM / 4 + 255) / 256), 256, 0, stream>>>(
        inputs, inbf, MROWS * IN_DIM / 4);
    transpose_conv_kernel<<<dim3(64, 64, 13), dim3(32, 8), 0, stream>>>(ta);

    gemm_kernel<1><<<dim3(DMODEL / 128, MROWS / 128), 256, 0, stream>>>(
        inbf, wt_in, b_in, nullptr, xbuf, MROWS, DMODEL, IN_DIM);

    for (int l = 0; l < 2; l++) {
        ln_kernel<true><<<MROWS / 4, 256, 0, stream>>>(xbuf, g1 + l * DMODEL, be1 + l * DMODEL, hbuf);
        gemm_kernel<6><<<dim3(DMODEL / 128, MROWS / 128), 256, 0, stream>>>(
            hbuf, wtq[l], bq + l * DMODEL, nullptr, qbf, MROWS, DMODEL, DMODEL);
        gemm_kernel<4><<<dim3(DMODEL / 128, MROWS / 128), 256, 0, stream>>>(
            hbuf, wtk[l], bk + l * DMODEL, nullptr, kbf, MROWS, DMODEL, DMODEL);
        gemm_kernel<5><<<dim3(DMODEL / 128, MROWS / 128), 256, 0, stream>>>(
            hbuf, wtv[l], bv + l * DMODEL, nullptr, vtbf, MROWS, DMODEL, DMODEL);
        fattn_kernel<<<dim3(S_LEN / 64, NHEAD, B_SZ), 256, 0, stream>>>(
            qbf, kbf, vtbf, rel_bias + (size_t)l * NHEAD * 127, lengths, aobuf);
        gemm_kernel<3><<<dim3(DMODEL / 128, MROWS / 128), 256, 0, stream>>>(
            aobuf, wto[l], bo + l * DMODEL, xbuf, xbuf, MROWS, DMODEL, DMODEL);
        ln_kernel<true><<<MROWS / 4, 256, 0, stream>>>(xbuf, g2 + l * DMODEL, be2 + l * DMODEL, hbuf);
        gemm_kernel<2><<<dim3(FF_DIM / 128, MROWS / 128), 256, 0, stream>>>(
            hbuf, wt1[l], b1 + l * FF_DIM, nullptr, tbuf, MROWS, FF_DIM, DMODEL);
        gemm_kernel<3><<<dim3(DMODEL / 128, MROWS / 128), 256, 0, stream>>>(
            tbuf, wt2[l], b2 + l * DMODEL, xbuf, xbuf, MROWS, DMODEL, FF_DIM);
    }
    ln_kernel<false><<<MROWS / 4, 256, 0, stream>>>(xbuf, gf, bef, d_out);
}

// Round 4
// 527.628 us; speedup vs baseline: 1.3179x; 1.3179x over previous
//
#include <hip/hip_runtime.h>
#include <hip/hip_bf16.h>

typedef unsigned short u16;
typedef __bf16 v8bf __attribute__((ext_vector_type(8)));
typedef float v4f __attribute__((ext_vector_type(4)));

#define B_SZ 8
#define S_LEN 1024
#define IN_DIM 256
#define DMODEL 512
#define NHEAD 8
#define DK 64
#define FF_DIM 2048
#define MROWS (B_SZ * S_LEN)   // 8192
#define QSCALE 0.1803368801111204f   // 0.125 * log2(e)

__device__ __forceinline__ u16 f2bf(float f) {
    unsigned int x = __float_as_uint(f);
    unsigned int r = (x + 0x7fffu + ((x >> 16) & 1u)) >> 16;
    return (u16)r;
}

// ---------------- elementwise f32 -> bf16 (inputs matrix) ----------------
__global__ __launch_bounds__(256) void conv_bf16_kernel(const float* __restrict__ in,
                                                        u16* __restrict__ out, int n4) {
    int i = blockIdx.x * 256 + threadIdx.x;
    if (i < n4) {
        float4 v = ((const float4*)in)[i];
        ushort4 o;
        o.x = f2bf(v.x); o.y = f2bf(v.y); o.z = f2bf(v.z); o.w = f2bf(v.w);
        ((ushort4*)out)[i] = o;
    }
}

// ------------- batched transpose+convert: (K,N) f32 -> (N,K) bf16 -------------
struct TDesc { const float* src; u16* dst; int K; int N; };
struct TArgs { TDesc d[13]; };

__global__ void transpose_conv_kernel(TArgs args) {
    TDesc t = args.d[blockIdx.z];
    int k0 = blockIdx.x * 32, n0 = blockIdx.y * 32;
    if (k0 >= t.K || n0 >= t.N) return;
    __shared__ float tile[32][33];
    int tx = threadIdx.x, ty = threadIdx.y;
#pragma unroll
    for (int j = 0; j < 4; j++) {
        int k = k0 + ty + j * 8;
        tile[ty + j * 8][tx] = t.src[(size_t)k * t.N + n0 + tx];
    }
    __syncthreads();
#pragma unroll
    for (int j = 0; j < 4; j++) {
        int n = n0 + ty + j * 8;
        t.dst[(size_t)n * t.K + k0 + tx] = f2bf(tile[tx][ty + j * 8]);
    }
}

// ---------------- LayerNorm: fp32 in -> bf16 (or fp32) out ----------------
template <bool OUT_BF16>
__global__ __launch_bounds__(256) void ln_kernel(const float* __restrict__ x,
                                                 const float* __restrict__ g,
                                                 const float* __restrict__ b,
                                                 void* __restrict__ out) {
    int row = blockIdx.x * 4 + (threadIdx.x >> 6);
    int lane = threadIdx.x & 63;
    const float4* xr = (const float4*)(x + (size_t)row * DMODEL);
    float4 v0 = xr[lane], v1 = xr[lane + 64];
    float s = v0.x + v0.y + v0.z + v0.w + v1.x + v1.y + v1.z + v1.w;
    float sq = v0.x * v0.x + v0.y * v0.y + v0.z * v0.z + v0.w * v0.w +
               v1.x * v1.x + v1.y * v1.y + v1.z * v1.z + v1.w * v1.w;
#pragma unroll
    for (int m = 1; m < 64; m <<= 1) {
        s += __shfl_xor(s, m);
        sq += __shfl_xor(sq, m);
    }
    float mean = s * (1.0f / DMODEL);
    float var = sq * (1.0f / DMODEL) - mean * mean;
    float rstd = rsqrtf(var + 1e-5f);
    const float4* g4 = (const float4*)g;
    const float4* b4 = (const float4*)b;
    float4 ga = g4[lane], gb = g4[lane + 64], ba = b4[lane], bb = b4[lane + 64];
    float4 r0, r1;
    r0.x = (v0.x - mean) * rstd * ga.x + ba.x;
    r0.y = (v0.y - mean) * rstd * ga.y + ba.y;
    r0.z = (v0.z - mean) * rstd * ga.z + ba.z;
    r0.w = (v0.w - mean) * rstd * ga.w + ba.w;
    r1.x = (v1.x - mean) * rstd * gb.x + bb.x;
    r1.y = (v1.y - mean) * rstd * gb.y + bb.y;
    r1.z = (v1.z - mean) * rstd * gb.z + bb.z;
    r1.w = (v1.w - mean) * rstd * gb.w + bb.w;
    if (OUT_BF16) {
        ushort4 o0, o1;
        o0.x = f2bf(r0.x); o0.y = f2bf(r0.y); o0.z = f2bf(r0.z); o0.w = f2bf(r0.w);
        o1.x = f2bf(r1.x); o1.y = f2bf(r1.y); o1.z = f2bf(r1.z); o1.w = f2bf(r1.w);
        ((ushort4*)out)[(size_t)row * 128 + lane] = o0;
        ((ushort4*)out)[(size_t)row * 128 + 64 + lane] = o1;
    } else {
        ((float4*)out)[(size_t)row * 128 + lane] = r0;
        ((float4*)out)[(size_t)row * 128 + 64 + lane] = r1;
    }
}

// ---------------- shared GEMM core: 128 x (NT*32) tile, BK=32 ----------------
// NT = n-frags per wave (2 -> BN=64 tile, 4 -> BN=128 tile)
template <int NT>
__device__ __forceinline__ void gemm_core(const u16* __restrict__ A, const u16* __restrict__ Bt,
                                          int K, v4f (&acc)[4][NT]) {
    constexpr int BN = NT * 32;
    constexpr int LDK = 40;  // 80B row stride -> 2-way (free) LDS aliasing on b128 reads
    __shared__ u16 As[128 * LDK];
    __shared__ u16 Bs[BN * LDK];
    int tid = threadIdx.x;
    int n0 = blockIdx.x * BN, m0 = blockIdx.y * 128;
    int w = tid >> 6, lane = tid & 63;
    int wr = (w >> 1) * 64, wc = (w & 1) * (BN / 2);
    int lr = lane & 15, lq = lane >> 4;

    v4f zero = {0.f, 0.f, 0.f, 0.f};
#pragma unroll
    for (int i = 0; i < 4; i++)
#pragma unroll
        for (int j = 0; j < NT; j++) acc[i][j] = zero;

    int srow = tid >> 2, scol = (tid & 3) * 8;
    const u16* Aptr = A + (size_t)(m0 + srow) * K + scol;
    const u16* Bptr = Bt + (size_t)(n0 + srow) * K + scol;
    size_t rstep = (size_t)64 * K;
    u16* AsW = &As[srow * LDK + scol];
    u16* BsW = &Bs[srow * LDK + scol];

    for (int k0 = 0; k0 < K; k0 += 32) {
        v8bf a0 = *(const v8bf*)Aptr;
        v8bf a1 = *(const v8bf*)(Aptr + rstep);
        v8bf b0 = *(const v8bf*)Bptr;
        v8bf b1;
        if constexpr (NT == 4) b1 = *(const v8bf*)(Bptr + rstep);
        __syncthreads();
        *(v8bf*)AsW = a0;
        *(v8bf*)(AsW + 64 * LDK) = a1;
        *(v8bf*)BsW = b0;
        if constexpr (NT == 4) *(v8bf*)(BsW + 64 * LDK) = b1;
        __syncthreads();
        v8bf af[4], bfr[NT];
#pragma unroll
        for (int i = 0; i < 4; i++)
            af[i] = *(const v8bf*)&As[(wr + i * 16 + lr) * LDK + lq * 8];
#pragma unroll
        for (int j = 0; j < NT; j++)
            bfr[j] = *(const v8bf*)&Bs[(wc + j * 16 + lr) * LDK + lq * 8];
#pragma unroll
        for (int mt = 0; mt < 4; mt++)
#pragma unroll
            for (int nt = 0; nt < NT; nt++)
                acc[mt][nt] = __builtin_amdgcn_mfma_f32_16x16x32_bf16(af[mt], bfr[nt], acc[mt][nt], 0, 0, 0);
        Aptr += 32;
        Bptr += 32;
    }
}

// ---- input projection: fp32 out + bias + sinusoid PE (N=512, BN=64) ----
__global__ __launch_bounds__(256) void gemm_in_kernel(const u16* __restrict__ A,
                                                      const u16* __restrict__ Bt,
                                                      const float* __restrict__ bias,
                                                      float* __restrict__ Out, int K) {
    v4f acc[4][2];
    gemm_core<2>(A, Bt, K, acc);
    int tid = threadIdx.x, w = tid >> 6, lane = tid & 63;
    int lr = lane & 15, lq = lane >> 4;
    int wr = (w >> 1) * 64, wc = (w & 1) * 32;
    int n0 = blockIdx.x * 64, m0 = blockIdx.y * 128;
#pragma unroll
    for (int mt = 0; mt < 4; mt++) {
#pragma unroll
        for (int nt = 0; nt < 2; nt++) {
            int col = n0 + wc + nt * 16 + lr;
            float bcol = bias[col];
            float freq = expf((float)(col & ~1) * (-0.017988946039015984f));
#pragma unroll
            for (int reg = 0; reg < 4; reg++) {
                int row = m0 + wr + mt * 16 + lq * 4 + reg;
                float ang = (float)(row & (S_LEN - 1)) * freq;
                float val = acc[mt][nt][reg] + bcol + ((col & 1) ? cosf(ang) : sinf(ang));
                Out[(size_t)row * DMODEL + col] = val;
            }
        }
    }
}

// ---- fused QKV projection: N=1536 (BN=128); segment block-uniform ----
// seg0: Q bf16 (+bq)*QSCALE ; seg1: K bf16 +bk ; seg2: V bf16 +bv, transposed store
__global__ __launch_bounds__(256) void gemm_qkv_kernel(const u16* __restrict__ A,
                                                       const u16* __restrict__ Bt,
                                                       const float* __restrict__ bq,
                                                       const float* __restrict__ bk,
                                                       const float* __restrict__ bv,
                                                       u16* __restrict__ Qo,
                                                       u16* __restrict__ Ko,
                                                       u16* __restrict__ Vto, int K) {
    v4f acc[4][4];
    gemm_core<4>(A, Bt, K, acc);
    int tid = threadIdx.x, w = tid >> 6, lane = tid & 63;
    int lr = lane & 15, lq = lane >> 4;
    int wr = (w >> 1) * 64, wc = (w & 1) * 64;
    int n0 = blockIdx.x * 128, m0 = blockIdx.y * 128;
    int seg = n0 >> 9;
#pragma unroll
    for (int mt = 0; mt < 4; mt++) {
#pragma unroll
        for (int nt = 0; nt < 4; nt++) {
            int col = (n0 + wc + nt * 16 + lr) & (DMODEL - 1);
            if (seg == 0) {
                float bcol = bq[col];
#pragma unroll
                for (int reg = 0; reg < 4; reg++) {
                    int row = m0 + wr + mt * 16 + lq * 4 + reg;
                    Qo[(size_t)row * DMODEL + col] = f2bf((acc[mt][nt][reg] + bcol) * QSCALE);
                }
            } else if (seg == 1) {
                float bcol = bk[col];
#pragma unroll
                for (int reg = 0; reg < 4; reg++) {
                    int row = m0 + wr + mt * 16 + lq * 4 + reg;
                    Ko[(size_t)row * DMODEL + col] = f2bf(acc[mt][nt][reg] + bcol);
                }
            } else {
                float bcol = bv[col];
                int row0 = m0 + wr + mt * 16 + lq * 4;
                int bb = row0 >> 10, s0 = row0 & (S_LEN - 1);
                ushort4 o;
                o.x = f2bf(acc[mt][nt][0] + bcol);
                o.y = f2bf(acc[mt][nt][1] + bcol);
                o.z = f2bf(acc[mt][nt][2] + bcol);
                o.w = f2bf(acc[mt][nt][3] + bcol);
                *(ushort4*)(Vto + ((size_t)(bb * DMODEL + col)) * S_LEN + s0) = o;
            }
        }
    }
}

// ---- FFN1: bf16 out + bias + ReLU (N=2048, BN=128) ----
__global__ __launch_bounds__(256) void gemm_relu_kernel(const u16* __restrict__ A,
                                                        const u16* __restrict__ Bt,
                                                        const float* __restrict__ bias,
                                                        u16* __restrict__ Out, int N, int K) {
    v4f acc[4][4];
    gemm_core<4>(A, Bt, K, acc);
    int tid = threadIdx.x, w = tid >> 6, lane = tid & 63;
    int lr = lane & 15, lq = lane >> 4;
    int wr = (w >> 1) * 64, wc = (w & 1) * 64;
    int n0 = blockIdx.x * 128, m0 = blockIdx.y * 128;
#pragma unroll
    for (int mt = 0; mt < 4; mt++) {
#pragma unroll
        for (int nt = 0; nt < 4; nt++) {
            int col = n0 + wc + nt * 16 + lr;
            float bcol = bias[col];
#pragma unroll
            for (int reg = 0; reg < 4; reg++) {
                int row = m0 + wr + mt * 16 + lq * 4 + reg;
                Out[(size_t)row * N + col] = f2bf(fmaxf(acc[mt][nt][reg] + bcol, 0.0f));
            }
        }
    }
}

// ---- O-proj / FFN2: fp32 out + bias + residual in-place (N=512, BN=64) ----
__global__ __launch_bounds__(256) void gemm_res_kernel(const u16* __restrict__ A,
                                                       const u16* __restrict__ Bt,
                                                       const float* __restrict__ bias,
                                                       float* __restrict__ Out, int K) {
    v4f acc[4][2];
    gemm_core<2>(A, Bt, K, acc);
    int tid = threadIdx.x, w = tid >> 6, lane = tid & 63;
    int lr = lane & 15, lq = lane >> 4;
    int wr = (w >> 1) * 64, wc = (w & 1) * 32;
    int n0 = blockIdx.x * 64, m0 = blockIdx.y * 128;
#pragma unroll
    for (int mt = 0; mt < 4; mt++) {
#pragma unroll
        for (int nt = 0; nt < 2; nt++) {
            int col = n0 + wc + nt * 16 + lr;
            float bcol = bias[col];
#pragma unroll
            for (int reg = 0; reg < 4; reg++) {
                int row = m0 + wr + mt * 16 + lq * 4 + reg;
                size_t idx = (size_t)row * DMODEL + col;
                Out[idx] = Out[idx] + acc[mt][nt][reg] + bcol;
            }
        }
    }
}

// ---------------- MFMA flash attention v3 ----------------
// LDS-staged K/V chunks (64 keys), fixed-max softmax (no shuffles in loop),
// q-tile 128/block, wave owns 32 q rows (2 m-frags) -> K-frag reuse x2.
// Q bf16 pre-scaled by 0.125*log2e; K bf16 [B*S][D]; Vt bf16 [(b*512+h*64+d)][s]
#define LDT 72
__global__ __launch_bounds__(256) void fattn_kernel(const u16* __restrict__ Qg,
                                                    const u16* __restrict__ Kg,
                                                    const u16* __restrict__ Vtg,
                                                    const float* __restrict__ rb,
                                                    const int* __restrict__ lengths,
                                                    u16* __restrict__ O) {
    int qt = blockIdx.x, h = blockIdx.y, b = blockIdx.z;
    int tid = threadIdx.x, w = tid >> 6, lane = tid & 63;
    int lr = lane & 15, lq = lane >> 4;
    __shared__ u16 Ks[64 * LDT];
    __shared__ u16 Vs[64 * LDT];
    __shared__ u16 Pw[4][32 * LDT];
    __shared__ float rbs[128];
    int len = lengths[b];
    if (tid < 127) rbs[tid] = rb[h * 127 + tid] * 1.4426950408889634f;  // fold log2(e)

    int qw = qt * 128 + w * 32;   // wave's 32 q rows
    v8bf qa[2][2];
#pragma unroll
    for (int mt = 0; mt < 2; mt++) {
        size_t qrow = ((size_t)(b * S_LEN + qw + mt * 16 + lr)) * DMODEL + h * DK;
        qa[mt][0] = *(const v8bf*)(Qg + qrow + lq * 8);
        qa[mt][1] = *(const v8bf*)(Qg + qrow + 32 + lq * 8);
    }

    v4f zero = {0.f, 0.f, 0.f, 0.f};
    v4f Oacc[2][4];
#pragma unroll
    for (int mt = 0; mt < 2; mt++)
#pragma unroll
        for (int nt = 0; nt < 4; nt++) Oacc[mt][nt] = zero;
    float lsum[2][4] = {{0.f, 0.f, 0.f, 0.f}, {0.f, 0.f, 0.f, 0.f}};

    const u16* Kbase = Kg + ((size_t)b * S_LEN) * DMODEL + h * DK;
    const u16* Vbase = Vtg + ((size_t)(b * DMODEL + h * DK)) * S_LEN;
    u16* P = Pw[w];
    int sr = tid >> 3, sc = (tid & 7) * 8;   // staging: 32 rows x 64 cols per pass

    for (int kb0 = 0; kb0 < len; kb0 += 64) {
        __syncthreads();   // prev-iter LDS reads done (also covers rbs on iter 0)
#pragma unroll
        for (int j = 0; j < 2; j++) {
            int rr = sr + j * 32;
            *(v8bf*)&Ks[rr * LDT + sc] = *(const v8bf*)(Kbase + (size_t)(kb0 + rr) * DMODEL + sc);
            *(v8bf*)&Vs[rr * LDT + sc] = *(const v8bf*)(Vbase + (size_t)rr * S_LEN + kb0 + sc);
        }
        __syncthreads();

        // K fragments (shared across both m-tiles)
        v8bf kf[4][2];
#pragma unroll
        for (int nt = 0; nt < 4; nt++) {
            kf[nt][0] = *(const v8bf*)&Ks[(nt * 16 + lr) * LDT + lq * 8];
            kf[nt][1] = *(const v8bf*)&Ks[(nt * 16 + lr) * LDT + 32 + lq * 8];
        }

        // S = Q @ K^T  (32q x 64k per wave)
        v4f S[2][4];
#pragma unroll
        for (int mt = 0; mt < 2; mt++)
#pragma unroll
            for (int nt = 0; nt < 4; nt++) {
                v4f s = __builtin_amdgcn_mfma_f32_16x16x32_bf16(qa[mt][0], kf[nt][0], zero, 0, 0, 0);
                S[mt][nt] = __builtin_amdgcn_mfma_f32_16x16x32_bf16(qa[mt][1], kf[nt][1], s, 0, 0, 0);
            }

        // bias + exp2 + P write (fixed max m=0)
        bool edge = (kb0 + 64 > len);
        int dmin = qw - (kb0 + 63), dmax = qw + 31 - kb0;
        bool perel = !(dmax <= -63 || dmin >= 63);
        float bconst = (dmax <= -63) ? rbs[0] : rbs[126];
#pragma unroll
        for (int mt = 0; mt < 2; mt++) {
#pragma unroll
            for (int nt = 0; nt < 4; nt++) {
                int k = kb0 + nt * 16 + lr;
#pragma unroll
                for (int r = 0; r < 4; r++) {
                    float s = S[mt][nt][r];
                    if (perel) {
                        int d = qw + mt * 16 + lq * 4 + r - k;
                        d = d < -63 ? -63 : (d > 63 ? 63 : d);
                        s += rbs[d + 63];
                    } else {
                        s += bconst;
                    }
                    float p = exp2f(s);
                    if (edge && k >= len) p = 0.f;
                    lsum[mt][r] += p;
                    P[(mt * 16 + lq * 4 + r) * LDT + nt * 16 + lr] = f2bf(p);
                }
            }
        }

        // V fragments (shared across both m-tiles) + O += P @ V
        v8bf vb[4][2];
#pragma unroll
        for (int nt = 0; nt < 4; nt++) {
            vb[nt][0] = *(const v8bf*)&Vs[(nt * 16 + lr) * LDT + lq * 8];
            vb[nt][1] = *(const v8bf*)&Vs[(nt * 16 + lr) * LDT + 32 + lq * 8];
        }
#pragma unroll
        for (int mt = 0; mt < 2; mt++) {
            v8bf pa0 = *(const v8bf*)&P[(mt * 16 + lr) * LDT + lq * 8];
            v8bf pa1 = *(const v8bf*)&P[(mt * 16 + lr) * LDT + 32 + lq * 8];
#pragma unroll
            for (int nt = 0; nt < 4; nt++) {
                Oacc[mt][nt] = __builtin_amdgcn_mfma_f32_16x16x32_bf16(pa0, vb[nt][0], Oacc[mt][nt], 0, 0, 0);
                Oacc[mt][nt] = __builtin_amdgcn_mfma_f32_16x16x32_bf16(pa1, vb[nt][1], Oacc[mt][nt], 0, 0, 0);
            }
        }
    }

    // final row-sum reduce (over the 16 lr lanes) + normalize + store
#pragma unroll
    for (int mt = 0; mt < 2; mt++) {
        float inv[4];
#pragma unroll
        for (int r = 0; r < 4; r++) {
            float s = lsum[mt][r];
            s += __shfl_xor(s, 1);
            s += __shfl_xor(s, 2);
            s += __shfl_xor(s, 4);
            s += __shfl_xor(s, 8);
            inv[r] = 1.0f / s;
        }
        size_t obase = ((size_t)(b * S_LEN + qw + mt * 16)) * DMODEL + h * DK;
#pragma unroll
        for (int nt = 0; nt < 4; nt++)
#pragma unroll
            for (int r = 0; r < 4; r++)
                O[obase + (size_t)(lq * 4 + r) * DMODEL + nt * 16 + lr] = f2bf(Oacc[mt][nt][r] * inv[r]);
    }
}

extern "C" void kernel_launch(void* const* d_in, const int* in_sizes, int n_in,
                              void* d_out, int out_size, void* d_ws, size_t ws_size,
                              hipStream_t stream) {
    const float* inputs   = (const float*)d_in[0];
    const int*   lengths  = (const int*)d_in[1];
    const float* W_in     = (const float*)d_in[2];
    const float* b_in     = (const float*)d_in[3];
    const float* Wq       = (const float*)d_in[4];
    const float* bq       = (const float*)d_in[5];
    const float* Wk       = (const float*)d_in[6];
    const float* bk       = (const float*)d_in[7];
    const float* Wv       = (const float*)d_in[8];
    const float* bv       = (const float*)d_in[9];
    const float* Wo       = (const float*)d_in[10];
    const float* bo       = (const float*)d_in[11];
    const float* rel_bias = (const float*)d_in[12];
    const float* W1       = (const float*)d_in[13];
    const float* b1       = (const float*)d_in[14];
    const float* W2       = (const float*)d_in[15];
    const float* b2       = (const float*)d_in[16];
    const float* g1       = (const float*)d_in[17];
    const float* be1      = (const float*)d_in[18];
    const float* g2       = (const float*)d_in[19];
    const float* be2      = (const float*)d_in[20];
    const float* gf       = (const float*)d_in[21];
    const float* bef      = (const float*)d_in[22];

    // ---- workspace layout ----
    char* ws = (char*)d_ws;
    float* xbuf = (float*)ws;          ws += (size_t)MROWS * DMODEL * 4;   // residual fp32
    u16* hbuf   = (u16*)ws;            ws += (size_t)MROWS * DMODEL * 2;   // LN output bf16
    u16* aobuf  = (u16*)ws;            ws += (size_t)MROWS * DMODEL * 2;   // attn output bf16
    u16* qbf    = (u16*)ws;                                                // union region (48MB):
    u16* kbf    = qbf + (size_t)MROWS * DMODEL;                            //  q/k/vt bf16 (24MB)
    u16* vtbf   = kbf + (size_t)MROWS * DMODEL;                            //  OR FFN mid (32MB)
    u16* tbuf   = qbf;                 ws += (size_t)MROWS * DMODEL * 4 * 3;
    u16* inbf   = (u16*)ws;            ws += (size_t)MROWS * IN_DIM * 2;   // bf16 inputs
    u16* wt_in  = (u16*)ws;            ws += (size_t)DMODEL * IN_DIM * 2;
    u16 *qkvw[2], *wto[2], *wt1[2], *wt2[2];
    for (int l = 0; l < 2; l++) { qkvw[l] = (u16*)ws; ws += (size_t)3 * DMODEL * DMODEL * 2; }
    for (int l = 0; l < 2; l++) { wto[l] = (u16*)ws; ws += (size_t)DMODEL * DMODEL * 2; }
    for (int l = 0; l < 2; l++) { wt1[l] = (u16*)ws; ws += (size_t)FF_DIM * DMODEL * 2; }
    for (int l = 0; l < 2; l++) { wt2[l] = (u16*)ws; ws += (size_t)DMODEL * FF_DIM * 2; }

    TArgs ta;
    int ti = 0;
    ta.d[ti++] = {W_in, wt_in, IN_DIM, DMODEL};
    for (int l = 0; l < 2; l++) {
        ta.d[ti++] = {Wq + (size_t)l * DMODEL * DMODEL, qkvw[l], DMODEL, DMODEL};
        ta.d[ti++] = {Wk + (size_t)l * DMODEL * DMODEL, qkvw[l] + (size_t)DMODEL * DMODEL, DMODEL, DMODEL};
        ta.d[ti++] = {Wv + (size_t)l * DMODEL * DMODEL, qkvw[l] + (size_t)2 * DMODEL * DMODEL, DMODEL, DMODEL};
        ta.d[ti++] = {Wo + (size_t)l * DMODEL * DMODEL, wto[l], DMODEL, DMODEL};
        ta.d[ti++] = {W1 + (size_t)l * DMODEL * FF_DIM, wt1[l], DMODEL, FF_DIM};
        ta.d[ti++] = {W2 + (size_t)l * FF_DIM * DMODEL, wt2[l], FF_DIM, DMODEL};
    }

    conv_bf16_kernel<<<dim3((MROWS * IN_DIM / 4 + 255) / 256), 256, 0, stream>>>(
        inputs, inbf, MROWS * IN_DIM / 4);
    transpose_conv_kernel<<<dim3(64, 64, 13), dim3(32, 8), 0, stream>>>(ta);

    gemm_in_kernel<<<dim3(DMODEL / 64, MROWS / 128), 256, 0, stream>>>(
        inbf, wt_in, b_in, xbuf, IN_DIM);

    for (int l = 0; l < 2; l++) {
        ln_kernel<true><<<MROWS / 4, 256, 0, stream>>>(xbuf, g1 + l * DMODEL, be1 + l * DMODEL, hbuf);
        gemm_qkv_kernel<<<dim3(3 * DMODEL / 128, MROWS / 128), 256, 0, stream>>>(
            hbuf, qkvw[l], bq + l * DMODEL, bk + l * DMODEL, bv + l * DMODEL,
            qbf, kbf, vtbf, DMODEL);
        fattn_kernel<<<dim3(S_LEN / 128, NHEAD, B_SZ), 256, 0, stream>>>(
            qbf, kbf, vtbf, rel_bias + (size_t)l * NHEAD * 127, lengths, aobuf);
        gemm_res_kernel<<<dim3(DMODEL / 64, MROWS / 128), 256, 0, stream>>>(
            aobuf, wto[l], bo + l * DMODEL, xbuf, DMODEL);
        ln_kernel<true><<<MROWS / 4, 256, 0, stream>>>(xbuf, g2 + l * DMODEL, be2 + l * DMODEL, hbuf);
        gemm_relu_kernel<<<dim3(FF_DIM / 128, MROWS / 128), 256, 0, stream>>>(
            hbuf, wt1[l], b1 + l * FF_DIM, tbuf, FF_DIM, DMODEL);
        gemm_res_kernel<<<dim3(DMODEL / 64, MROWS / 128), 256, 0, stream>>>(
            tbuf, wt2[l], b2 + l * DMODEL, xbuf, FF_DIM);
    }
    ln_kernel<false><<<MROWS / 4, 256, 0, stream>>>(xbuf, gf, bef, d_out);
}

// Round 5
// 526.457 us; speedup vs baseline: 1.3209x; 1.0022x over previous
//
#include <hip/hip_runtime.h>
#include <hip/hip_bf16.h>

typedef unsigned short u16;
typedef __bf16 v8bf __attribute__((ext_vector_type(8)));
typedef float v4f __attribute__((ext_vector_type(4)));

#define B_SZ 8
#define S_LEN 1024
#define IN_DIM 256
#define DMODEL 512
#define NHEAD 8
#define DK 64
#define FF_DIM 2048
#define MROWS (B_SZ * S_LEN)   // 8192
#define QSCALE 0.1803368801111204f   // 0.125 * log2(e)

__device__ __forceinline__ u16 f2bf(float f) {
    unsigned int x = __float_as_uint(f);
    unsigned int r = (x + 0x7fffu + ((x >> 16) & 1u)) >> 16;
    return (u16)r;
}

// async global->LDS DMA, 16B per lane; lds dest must be wave-uniform base (lane*16 auto)
__device__ __forceinline__ void gl16(const u16* g, u16* l) {
    __builtin_amdgcn_global_load_lds((const __attribute__((address_space(1))) unsigned int*)g,
                                     (__attribute__((address_space(3))) unsigned int*)l, 16, 0, 0);
}

// ---------------- elementwise f32 -> bf16 (inputs matrix) ----------------
__global__ __launch_bounds__(256) void conv_bf16_kernel(const float* __restrict__ in,
                                                        u16* __restrict__ out, int n4) {
    int i = blockIdx.x * 256 + threadIdx.x;
    if (i < n4) {
        float4 v = ((const float4*)in)[i];
        ushort4 o;
        o.x = f2bf(v.x); o.y = f2bf(v.y); o.z = f2bf(v.z); o.w = f2bf(v.w);
        ((ushort4*)out)[i] = o;
    }
}

// ------------- batched transpose+convert: (K,N) f32 -> (N,K) bf16 -------------
struct TDesc { const float* src; u16* dst; int K; int N; };
struct TArgs { TDesc d[13]; };

__global__ void transpose_conv_kernel(TArgs args) {
    TDesc t = args.d[blockIdx.z];
    int k0 = blockIdx.x * 32, n0 = blockIdx.y * 32;
    if (k0 >= t.K || n0 >= t.N) return;
    __shared__ float tile[32][33];
    int tx = threadIdx.x, ty = threadIdx.y;
#pragma unroll
    for (int j = 0; j < 4; j++) {
        int k = k0 + ty + j * 8;
        tile[ty + j * 8][tx] = t.src[(size_t)k * t.N + n0 + tx];
    }
    __syncthreads();
#pragma unroll
    for (int j = 0; j < 4; j++) {
        int n = n0 + ty + j * 8;
        t.dst[(size_t)n * t.K + k0 + tx] = f2bf(tile[tx][ty + j * 8]);
    }
}

// ---------------- LayerNorm: fp32 in -> bf16 (or fp32) out ----------------
template <bool OUT_BF16>
__global__ __launch_bounds__(256) void ln_kernel(const float* __restrict__ x,
                                                 const float* __restrict__ g,
                                                 const float* __restrict__ b,
                                                 void* __restrict__ out) {
    int row = blockIdx.x * 4 + (threadIdx.x >> 6);
    int lane = threadIdx.x & 63;
    const float4* xr = (const float4*)(x + (size_t)row * DMODEL);
    float4 v0 = xr[lane], v1 = xr[lane + 64];
    float s = v0.x + v0.y + v0.z + v0.w + v1.x + v1.y + v1.z + v1.w;
    float sq = v0.x * v0.x + v0.y * v0.y + v0.z * v0.z + v0.w * v0.w +
               v1.x * v1.x + v1.y * v1.y + v1.z * v1.z + v1.w * v1.w;
#pragma unroll
    for (int m = 1; m < 64; m <<= 1) {
        s += __shfl_xor(s, m);
        sq += __shfl_xor(sq, m);
    }
    float mean = s * (1.0f / DMODEL);
    float var = sq * (1.0f / DMODEL) - mean * mean;
    float rstd = rsqrtf(var + 1e-5f);
    const float4* g4 = (const float4*)g;
    const float4* b4 = (const float4*)b;
    float4 ga = g4[lane], gb = g4[lane + 64], ba = b4[lane], bb = b4[lane + 64];
    float4 r0, r1;
    r0.x = (v0.x - mean) * rstd * ga.x + ba.x;
    r0.y = (v0.y - mean) * rstd * ga.y + ba.y;
    r0.z = (v0.z - mean) * rstd * ga.z + ba.z;
    r0.w = (v0.w - mean) * rstd * ga.w + ba.w;
    r1.x = (v1.x - mean) * rstd * gb.x + bb.x;
    r1.y = (v1.y - mean) * rstd * gb.y + bb.y;
    r1.z = (v1.z - mean) * rstd * gb.z + bb.z;
    r1.w = (v1.w - mean) * rstd * gb.w + bb.w;
    if (OUT_BF16) {
        ushort4 o0, o1;
        o0.x = f2bf(r0.x); o0.y = f2bf(r0.y); o0.z = f2bf(r0.z); o0.w = f2bf(r0.w);
        o1.x = f2bf(r1.x); o1.y = f2bf(r1.y); o1.z = f2bf(r1.z); o1.w = f2bf(r1.w);
        ((ushort4*)out)[(size_t)row * 128 + lane] = o0;
        ((ushort4*)out)[(size_t)row * 128 + 64 + lane] = o1;
    } else {
        ((float4*)out)[(size_t)row * 128 + lane] = r0;
        ((float4*)out)[(size_t)row * 128 + 64 + lane] = r1;
    }
}

// ------------- shared GEMM core (m97 structure): 128 x (NT*32) tile, BK=32 -------------
// global_load_lds width-16 staging into unpadded row-major LDS tiles; 2-barrier K-loop.
template <int NT>
__device__ __forceinline__ void gemm_core(const u16* __restrict__ A, const u16* __restrict__ Bt,
                                          int K, v4f (&acc)[4][NT]) {
    constexpr int BN = NT * 32;
    __shared__ u16 As[128 * 32];
    __shared__ u16 Bs[BN * 32];
    int tid = threadIdx.x;
    int n0 = blockIdx.x * BN, m0 = blockIdx.y * 128;
    int w = tid >> 6, lane = tid & 63;
    int wr = (w >> 1) * 64, wc = (w & 1) * (BN / 2);
    int lr = lane & 15, lq = lane >> 4;

    v4f zero = {0.f, 0.f, 0.f, 0.f};
#pragma unroll
    for (int i = 0; i < 4; i++)
#pragma unroll
        for (int j = 0; j < NT; j++) acc[i][j] = zero;

    int srow = lane >> 2, scol = (lane & 3) * 8;   // 16 rows x 32 cols per 1KB issue
    const u16* gA0 = A + (size_t)(m0 + 32 * w + srow) * K + scol;
    const u16* gA1 = gA0 + (size_t)16 * K;
    u16* lA0 = As + (32 * w) * 32;        // wave-uniform
    u16* lA1 = As + (32 * w + 16) * 32;
    const u16* gB0;
    const u16* gB1 = nullptr;
    u16* lB0;
    u16* lB1 = nullptr;
    if constexpr (NT == 4) {
        gB0 = Bt + (size_t)(n0 + 32 * w + srow) * K + scol;
        gB1 = gB0 + (size_t)16 * K;
        lB0 = Bs + (32 * w) * 32;
        lB1 = Bs + (32 * w + 16) * 32;
    } else {
        gB0 = Bt + (size_t)(n0 + 16 * w + srow) * K + scol;
        lB0 = Bs + (16 * w) * 32;
    }

    for (int k0 = 0; k0 < K; k0 += 32) {
        gl16(gA0, lA0);
        gl16(gA1, lA1);
        gl16(gB0, lB0);
        if constexpr (NT == 4) gl16(gB1, lB1);
        __syncthreads();   // vmcnt drain -> LDS tiles ready
        v8bf af[4], bfr[NT];
#pragma unroll
        for (int i = 0; i < 4; i++)
            af[i] = *(const v8bf*)&As[(wr + i * 16 + lr) * 32 + lq * 8];
#pragma unroll
        for (int j = 0; j < NT; j++)
            bfr[j] = *(const v8bf*)&Bs[(wc + j * 16 + lr) * 32 + lq * 8];
#pragma unroll
        for (int mt = 0; mt < 4; mt++)
#pragma unroll
            for (int nt = 0; nt < NT; nt++)
                acc[mt][nt] = __builtin_amdgcn_mfma_f32_16x16x32_bf16(af[mt], bfr[nt], acc[mt][nt], 0, 0, 0);
        __syncthreads();   // frag reads done before next DMA overwrites
        gA0 += 32; gA1 += 32; gB0 += 32;
        if constexpr (NT == 4) gB1 += 32;
    }
}

// ---- input projection: fp32 out + bias + sinusoid PE (N=512, BN=64) ----
__global__ __launch_bounds__(256) void gemm_in_kernel(const u16* __restrict__ A,
                                                      const u16* __restrict__ Bt,
                                                      const float* __restrict__ bias,
                                                      float* __restrict__ Out, int K) {
    v4f acc[4][2];
    gemm_core<2>(A, Bt, K, acc);
    int tid = threadIdx.x, w = tid >> 6, lane = tid & 63;
    int lr = lane & 15, lq = lane >> 4;
    int wr = (w >> 1) * 64, wc = (w & 1) * 32;
    int n0 = blockIdx.x * 64, m0 = blockIdx.y * 128;
#pragma unroll
    for (int mt = 0; mt < 4; mt++) {
#pragma unroll
        for (int nt = 0; nt < 2; nt++) {
            int col = n0 + wc + nt * 16 + lr;
            float bcol = bias[col];
            float freq = expf((float)(col & ~1) * (-0.017988946039015984f));
#pragma unroll
            for (int reg = 0; reg < 4; reg++) {
                int row = m0 + wr + mt * 16 + lq * 4 + reg;
                float ang = (float)(row & (S_LEN - 1)) * freq;
                float val = acc[mt][nt][reg] + bcol + ((col & 1) ? cosf(ang) : sinf(ang));
                Out[(size_t)row * DMODEL + col] = val;
            }
        }
    }
}

// ---- fused QKV projection: N=1536 (BN=128); segment block-uniform ----
__global__ __launch_bounds__(256) void gemm_qkv_kernel(const u16* __restrict__ A,
                                                       const u16* __restrict__ Bt,
                                                       const float* __restrict__ bq,
                                                       const float* __restrict__ bk,
                                                       const float* __restrict__ bv,
                                                       u16* __restrict__ Qo,
                                                       u16* __restrict__ Ko,
                                                       u16* __restrict__ Vto, int K) {
    v4f acc[4][4];
    gemm_core<4>(A, Bt, K, acc);
    int tid = threadIdx.x, w = tid >> 6, lane = tid & 63;
    int lr = lane & 15, lq = lane >> 4;
    int wr = (w >> 1) * 64, wc = (w & 1) * 64;
    int n0 = blockIdx.x * 128, m0 = blockIdx.y * 128;
    int seg = n0 >> 9;
#pragma unroll
    for (int mt = 0; mt < 4; mt++) {
#pragma unroll
        for (int nt = 0; nt < 4; nt++) {
            int col = (n0 + wc + nt * 16 + lr) & (DMODEL - 1);
            if (seg == 0) {
                float bcol = bq[col];
#pragma unroll
                for (int reg = 0; reg < 4; reg++) {
                    int row = m0 + wr + mt * 16 + lq * 4 + reg;
                    Qo[(size_t)row * DMODEL + col] = f2bf((acc[mt][nt][reg] + bcol) * QSCALE);
                }
            } else if (seg == 1) {
                float bcol = bk[col];
#pragma unroll
                for (int reg = 0; reg < 4; reg++) {
                    int row = m0 + wr + mt * 16 + lq * 4 + reg;
                    Ko[(size_t)row * DMODEL + col] = f2bf(acc[mt][nt][reg] + bcol);
                }
            } else {
                float bcol = bv[col];
                int row0 = m0 + wr + mt * 16 + lq * 4;
                int bb = row0 >> 10, s0 = row0 & (S_LEN - 1);
                ushort4 o;
                o.x = f2bf(acc[mt][nt][0] + bcol);
                o.y = f2bf(acc[mt][nt][1] + bcol);
                o.z = f2bf(acc[mt][nt][2] + bcol);
                o.w = f2bf(acc[mt][nt][3] + bcol);
                *(ushort4*)(Vto + ((size_t)(bb * DMODEL + col)) * S_LEN + s0) = o;
            }
        }
    }
}

// ---- FFN1: bf16 out + bias + ReLU (N=2048, BN=128) ----
__global__ __launch_bounds__(256) void gemm_relu_kernel(const u16* __restrict__ A,
                                                        const u16* __restrict__ Bt,
                                                        const float* __restrict__ bias,
                                                        u16* __restrict__ Out, int N, int K) {
    v4f acc[4][4];
    gemm_core<4>(A, Bt, K, acc);
    int tid = threadIdx.x, w = tid >> 6, lane = tid & 63;
    int lr = lane & 15, lq = lane >> 4;
    int wr = (w >> 1) * 64, wc = (w & 1) * 64;
    int n0 = blockIdx.x * 128, m0 = blockIdx.y * 128;
#pragma unroll
    for (int mt = 0; mt < 4; mt++) {
#pragma unroll
        for (int nt = 0; nt < 4; nt++) {
            int col = n0 + wc + nt * 16 + lr;
            float bcol = bias[col];
#pragma unroll
            for (int reg = 0; reg < 4; reg++) {
                int row = m0 + wr + mt * 16 + lq * 4 + reg;
                Out[(size_t)row * N + col] = f2bf(fmaxf(acc[mt][nt][reg] + bcol, 0.0f));
            }
        }
    }
}

// ---- O-proj / FFN2: fp32 out + bias + residual in-place (N=512, BN=64) ----
__global__ __launch_bounds__(256) void gemm_res_kernel(const u16* __restrict__ A,
                                                       const u16* __restrict__ Bt,
                                                       const float* __restrict__ bias,
                                                       float* __restrict__ Out, int K) {
    v4f acc[4][2];
    gemm_core<2>(A, Bt, K, acc);
    int tid = threadIdx.x, w = tid >> 6, lane = tid & 63;
    int lr = lane & 15, lq = lane >> 4;
    int wr = (w >> 1) * 64, wc = (w & 1) * 32;
    int n0 = blockIdx.x * 64, m0 = blockIdx.y * 128;
#pragma unroll
    for (int mt = 0; mt < 4; mt++) {
#pragma unroll
        for (int nt = 0; nt < 2; nt++) {
            int col = n0 + wc + nt * 16 + lr;
            float bcol = bias[col];
#pragma unroll
            for (int reg = 0; reg < 4; reg++) {
                int row = m0 + wr + mt * 16 + lq * 4 + reg;
                size_t idx = (size_t)row * DMODEL + col;
                Out[idx] = Out[idx] + acc[mt][nt][reg] + bcol;
            }
        }
    }
}

// ---------------- MFMA flash attention (r4 structure, unchanged) ----------------
#define LDT 72
__global__ __launch_bounds__(256) void fattn_kernel(const u16* __restrict__ Qg,
                                                    const u16* __restrict__ Kg,
                                                    const u16* __restrict__ Vtg,
                                                    const float* __restrict__ rb,
                                                    const int* __restrict__ lengths,
                                                    u16* __restrict__ O) {
    int qt = blockIdx.x, h = blockIdx.y, b = blockIdx.z;
    int tid = threadIdx.x, w = tid >> 6, lane = tid & 63;
    int lr = lane & 15, lq = lane >> 4;
    __shared__ u16 Ks[64 * LDT];
    __shared__ u16 Vs[64 * LDT];
    __shared__ u16 Pw[4][32 * LDT];
    __shared__ float rbs[128];
    int len = lengths[b];
    if (tid < 127) rbs[tid] = rb[h * 127 + tid] * 1.4426950408889634f;  // fold log2(e)

    int qw = qt * 128 + w * 32;   // wave's 32 q rows
    v8bf qa[2][2];
#pragma unroll
    for (int mt = 0; mt < 2; mt++) {
        size_t qrow = ((size_t)(b * S_LEN + qw + mt * 16 + lr)) * DMODEL + h * DK;
        qa[mt][0] = *(const v8bf*)(Qg + qrow + lq * 8);
        qa[mt][1] = *(const v8bf*)(Qg + qrow + 32 + lq * 8);
    }

    v4f zero = {0.f, 0.f, 0.f, 0.f};
    v4f Oacc[2][4];
#pragma unroll
    for (int mt = 0; mt < 2; mt++)
#pragma unroll
        for (int nt = 0; nt < 4; nt++) Oacc[mt][nt] = zero;
    float lsum[2][4] = {{0.f, 0.f, 0.f, 0.f}, {0.f, 0.f, 0.f, 0.f}};

    const u16* Kbase = Kg + ((size_t)b * S_LEN) * DMODEL + h * DK;
    const u16* Vbase = Vtg + ((size_t)(b * DMODEL + h * DK)) * S_LEN;
    u16* P = Pw[w];
    int sr = tid >> 3, sc = (tid & 7) * 8;

    for (int kb0 = 0; kb0 < len; kb0 += 64) {
        __syncthreads();
#pragma unroll
        for (int j = 0; j < 2; j++) {
            int rr = sr + j * 32;
            *(v8bf*)&Ks[rr * LDT + sc] = *(const v8bf*)(Kbase + (size_t)(kb0 + rr) * DMODEL + sc);
            *(v8bf*)&Vs[rr * LDT + sc] = *(const v8bf*)(Vbase + (size_t)rr * S_LEN + kb0 + sc);
        }
        __syncthreads();

        v8bf kf[4][2];
#pragma unroll
        for (int nt = 0; nt < 4; nt++) {
            kf[nt][0] = *(const v8bf*)&Ks[(nt * 16 + lr) * LDT + lq * 8];
            kf[nt][1] = *(const v8bf*)&Ks[(nt * 16 + lr) * LDT + 32 + lq * 8];
        }

        v4f S[2][4];
#pragma unroll
        for (int mt = 0; mt < 2; mt++)
#pragma unroll
            for (int nt = 0; nt < 4; nt++) {
                v4f s = __builtin_amdgcn_mfma_f32_16x16x32_bf16(qa[mt][0], kf[nt][0], zero, 0, 0, 0);
                S[mt][nt] = __builtin_amdgcn_mfma_f32_16x16x32_bf16(qa[mt][1], kf[nt][1], s, 0, 0, 0);
            }

        bool edge = (kb0 + 64 > len);
        int dmin = qw - (kb0 + 63), dmax = qw + 31 - kb0;
        bool perel = !(dmax <= -63 || dmin >= 63);
        float bconst = (dmax <= -63) ? rbs[0] : rbs[126];
#pragma unroll
        for (int mt = 0; mt < 2; mt++) {
#pragma unroll
            for (int nt = 0; nt < 4; nt++) {
                int k = kb0 + nt * 16 + lr;
#pragma unroll
                for (int r = 0; r < 4; r++) {
                    float s = S[mt][nt][r];
                    if (perel) {
                        int d = qw + mt * 16 + lq * 4 + r - k;
                        d = d < -63 ? -63 : (d > 63 ? 63 : d);
                        s += rbs[d + 63];
                    } else {
                        s += bconst;
                    }
                    float p = exp2f(s);
                    if (edge && k >= len) p = 0.f;
                    lsum[mt][r] += p;
                    P[(mt * 16 + lq * 4 + r) * LDT + nt * 16 + lr] = f2bf(p);
                }
            }
        }

        v8bf vb[4][2];
#pragma unroll
        for (int nt = 0; nt < 4; nt++) {
            vb[nt][0] = *(const v8bf*)&Vs[(nt * 16 + lr) * LDT + lq * 8];
            vb[nt][1] = *(const v8bf*)&Vs[(nt * 16 + lr) * LDT + 32 + lq * 8];
        }
#pragma unroll
        for (int mt = 0; mt < 2; mt++) {
            v8bf pa0 = *(const v8bf*)&P[(mt * 16 + lr) * LDT + lq * 8];
            v8bf pa1 = *(const v8bf*)&P[(mt * 16 + lr) * LDT + 32 + lq * 8];
#pragma unroll
            for (int nt = 0; nt < 4; nt++) {
                Oacc[mt][nt] = __builtin_amdgcn_mfma_f32_16x16x32_bf16(pa0, vb[nt][0], Oacc[mt][nt], 0, 0, 0);
                Oacc[mt][nt] = __builtin_amdgcn_mfma_f32_16x16x32_bf16(pa1, vb[nt][1], Oacc[mt][nt], 0, 0, 0);
            }
        }
    }

#pragma unroll
    for (int mt = 0; mt < 2; mt++) {
        float inv[4];
#pragma unroll
        for (int r = 0; r < 4; r++) {
            float s = lsum[mt][r];
            s += __shfl_xor(s, 1);
            s += __shfl_xor(s, 2);
            s += __shfl_xor(s, 4);
            s += __shfl_xor(s, 8);
            inv[r] = 1.0f / s;
        }
        size_t obase = ((size_t)(b * S_LEN + qw + mt * 16)) * DMODEL + h * DK;
#pragma unroll
        for (int nt = 0; nt < 4; nt++)
#pragma unroll
            for (int r = 0; r < 4; r++)
                O[obase + (size_t)(lq * 4 + r) * DMODEL + nt * 16 + lr] = f2bf(Oacc[mt][nt][r] * inv[r]);
    }
}

extern "C" void kernel_launch(void* const* d_in, const int* in_sizes, int n_in,
                              void* d_out, int out_size, void* d_ws, size_t ws_size,
                              hipStream_t stream) {
    const float* inputs   = (const float*)d_in[0];
    const int*   lengths  = (const int*)d_in[1];
    const float* W_in     = (const float*)d_in[2];
    const float* b_in     = (const float*)d_in[3];
    const float* Wq       = (const float*)d_in[4];
    const float* bq       = (const float*)d_in[5];
    const float* Wk       = (const float*)d_in[6];
    const float* bk       = (const float*)d_in[7];
    const float* Wv       = (const float*)d_in[8];
    const float* bv       = (const float*)d_in[9];
    const float* Wo       = (const float*)d_in[10];
    const float* bo       = (const float*)d_in[11];
    const float* rel_bias = (const float*)d_in[12];
    const float* W1       = (const float*)d_in[13];
    const float* b1       = (const float*)d_in[14];
    const float* W2       = (const float*)d_in[15];
    const float* b2       = (const float*)d_in[16];
    const float* g1       = (const float*)d_in[17];
    const float* be1      = (const float*)d_in[18];
    const float* g2       = (const float*)d_in[19];
    const float* be2      = (const float*)d_in[20];
    const float* gf       = (const float*)d_in[21];
    const float* bef      = (const float*)d_in[22];

    // ---- workspace layout ----
    char* ws = (char*)d_ws;
    float* xbuf = (float*)ws;          ws += (size_t)MROWS * DMODEL * 4;   // residual fp32
    u16* hbuf   = (u16*)ws;            ws += (size_t)MROWS * DMODEL * 2;   // LN output bf16
    u16* aobuf  = (u16*)ws;            ws += (size_t)MROWS * DMODEL * 2;   // attn output bf16
    u16* qbf    = (u16*)ws;                                                // union region (48MB):
    u16* kbf    = qbf + (size_t)MROWS * DMODEL;                            //  q/k/vt bf16 (24MB)
    u16* vtbf   = kbf + (size_t)MROWS * DMODEL;                            //  OR FFN mid (32MB)
    u16* tbuf   = qbf;                 ws += (size_t)MROWS * DMODEL * 4 * 3;
    u16* inbf   = (u16*)ws;            ws += (size_t)MROWS * IN_DIM * 2;   // bf16 inputs
    u16* wt_in  = (u16*)ws;            ws += (size_t)DMODEL * IN_DIM * 2;
    u16 *qkvw[2], *wto[2], *wt1[2], *wt2[2];
    for (int l = 0; l < 2; l++) { qkvw[l] = (u16*)ws; ws += (size_t)3 * DMODEL * DMODEL * 2; }
    for (int l = 0; l < 2; l++) { wto[l] = (u16*)ws; ws += (size_t)DMODEL * DMODEL * 2; }
    for (int l = 0; l < 2; l++) { wt1[l] = (u16*)ws; ws += (size_t)FF_DIM * DMODEL * 2; }
    for (int l = 0; l < 2; l++) { wt2[l] = (u16*)ws; ws += (size_t)DMODEL * FF_DIM * 2; }

    TArgs ta;
    int ti = 0;
    ta.d[ti++] = {W_in, wt_in, IN_DIM, DMODEL};
    for (int l = 0; l < 2; l++) {
        ta.d[ti++] = {Wq + (size_t)l * DMODEL * DMODEL, qkvw[l], DMODEL, DMODEL};
        ta.d[ti++] = {Wk + (size_t)l * DMODEL * DMODEL, qkvw[l] + (size_t)DMODEL * DMODEL, DMODEL, DMODEL};
        ta.d[ti++] = {Wv + (size_t)l * DMODEL * DMODEL, qkvw[l] + (size_t)2 * DMODEL * DMODEL, DMODEL, DMODEL};
        ta.d[ti++] = {Wo + (size_t)l * DMODEL * DMODEL, wto[l], DMODEL, DMODEL};
        ta.d[ti++] = {W1 + (size_t)l * DMODEL * FF_DIM, wt1[l], DMODEL, FF_DIM};
        ta.d[ti++] = {W2 + (size_t)l * FF_DIM * DMODEL, wt2[l], FF_DIM, DMODEL};
    }

    conv_bf16_kernel<<<dim3((MROWS * IN_DIM / 4 + 255) / 256), 256, 0, stream>>>(
        inputs, inbf, MROWS * IN_DIM / 4);
    transpose_conv_kernel<<<dim3(64, 64, 13), dim3(32, 8), 0, stream>>>(ta);

    gemm_in_kernel<<<dim3(DMODEL / 64, MROWS / 128), 256, 0, stream>>>(
        inbf, wt_in, b_in, xbuf, IN_DIM);

    for (int l = 0; l < 2; l++) {
        ln_kernel<true><<<MROWS / 4, 256, 0, stream>>>(xbuf, g1 + l * DMODEL, be1 + l * DMODEL, hbuf);
        gemm_qkv_kernel<<<dim3(3 * DMODEL / 128, MROWS / 128), 256, 0, stream>>>(
            hbuf, qkvw[l], bq + l * DMODEL, bk + l * DMODEL, bv + l * DMODEL,
            qbf, kbf, vtbf, DMODEL);
        fattn_kernel<<<dim3(S_LEN / 128, NHEAD, B_SZ), 256, 0, stream>>>(
            qbf, kbf, vtbf, rel_bias + (size_t)l * NHEAD * 127, lengths, aobuf);
        gemm_res_kernel<<<dim3(DMODEL / 64, MROWS / 128), 256, 0, stream>>>(
            aobuf, wto[l], bo + l * DMODEL, xbuf, DMODEL);
        ln_kernel<true><<<MROWS / 4, 256, 0, stream>>>(xbuf, g2 + l * DMODEL, be2 + l * DMODEL, hbuf);
        gemm_relu_kernel<<<dim3(FF_DIM / 128, MROWS / 128), 256, 0, stream>>>(
            hbuf, wt1[l], b1 + l * FF_DIM, tbuf, FF_DIM, DMODEL);
        gemm_res_kernel<<<dim3(DMODEL / 64, MROWS / 128), 256, 0, stream>>>(
            tbuf, wt2[l], b2 + l * DMODEL, xbuf, FF_DIM);
    }
    ln_kernel<false><<<MROWS / 4, 256, 0, stream>>>(xbuf, gf, bef, d_out);
}

// Round 6
// 491.027 us; speedup vs baseline: 1.4162x; 1.0722x over previous
//
#include <hip/hip_runtime.h>
#include <hip/hip_bf16.h>

typedef unsigned short u16;
typedef __bf16 v8bf __attribute__((ext_vector_type(8)));
typedef float v4f __attribute__((ext_vector_type(4)));

#define B_SZ 8
#define S_LEN 1024
#define IN_DIM 256
#define DMODEL 512
#define NHEAD 8
#define DK 64
#define FF_DIM 2048
#define MROWS (B_SZ * S_LEN)   // 8192
#define QSCALE 0.1803368801111204f   // 0.125 * log2(e)

__device__ __forceinline__ u16 f2bf(float f) {
    unsigned int x = __float_as_uint(f);
    unsigned int r = (x + 0x7fffu + ((x >> 16) & 1u)) >> 16;
    return (u16)r;
}

// async global->LDS DMA, 16B per lane; lds dest is wave-uniform base + lane*16
__device__ __forceinline__ void gl16(const u16* g, u16* l) {
    __builtin_amdgcn_global_load_lds((const __attribute__((address_space(1))) unsigned int*)g,
                                     (__attribute__((address_space(3))) unsigned int*)l, 16, 0, 0);
}

// ---------------- elementwise f32 -> bf16 (inputs matrix) ----------------
__global__ __launch_bounds__(256) void conv_bf16_kernel(const float* __restrict__ in,
                                                        u16* __restrict__ out, int n4) {
    int i = blockIdx.x * 256 + threadIdx.x;
    if (i < n4) {
        float4 v = ((const float4*)in)[i];
        ushort4 o;
        o.x = f2bf(v.x); o.y = f2bf(v.y); o.z = f2bf(v.z); o.w = f2bf(v.w);
        ((ushort4*)out)[i] = o;
    }
}

// ------------- batched transpose+convert: (K,N) f32 -> (N,K) bf16 -------------
struct TDesc { const float* src; u16* dst; int K; int N; };
struct TArgs { TDesc d[13]; };

__global__ void transpose_conv_kernel(TArgs args) {
    TDesc t = args.d[blockIdx.z];
    int k0 = blockIdx.x * 32, n0 = blockIdx.y * 32;
    if (k0 >= t.K || n0 >= t.N) return;
    __shared__ float tile[32][33];
    int tx = threadIdx.x, ty = threadIdx.y;
#pragma unroll
    for (int j = 0; j < 4; j++) {
        int k = k0 + ty + j * 8;
        tile[ty + j * 8][tx] = t.src[(size_t)k * t.N + n0 + tx];
    }
    __syncthreads();
#pragma unroll
    for (int j = 0; j < 4; j++) {
        int n = n0 + ty + j * 8;
        t.dst[(size_t)n * t.K + k0 + tx] = f2bf(tile[tx][ty + j * 8]);
    }
}

// ---------------- LayerNorm: fp32 in -> bf16 (or fp32) out ----------------
template <bool OUT_BF16>
__global__ __launch_bounds__(256) void ln_kernel(const float* __restrict__ x,
                                                 const float* __restrict__ g,
                                                 const float* __restrict__ b,
                                                 void* __restrict__ out) {
    int row = blockIdx.x * 4 + (threadIdx.x >> 6);
    int lane = threadIdx.x & 63;
    const float4* xr = (const float4*)(x + (size_t)row * DMODEL);
    float4 v0 = xr[lane], v1 = xr[lane + 64];
    float s = v0.x + v0.y + v0.z + v0.w + v1.x + v1.y + v1.z + v1.w;
    float sq = v0.x * v0.x + v0.y * v0.y + v0.z * v0.z + v0.w * v0.w +
               v1.x * v1.x + v1.y * v1.y + v1.z * v1.z + v1.w * v1.w;
#pragma unroll
    for (int m = 1; m < 64; m <<= 1) {
        s += __shfl_xor(s, m);
        sq += __shfl_xor(sq, m);
    }
    float mean = s * (1.0f / DMODEL);
    float var = sq * (1.0f / DMODEL) - mean * mean;
    float rstd = rsqrtf(var + 1e-5f);
    const float4* g4 = (const float4*)g;
    const float4* b4 = (const float4*)b;
    float4 ga = g4[lane], gb = g4[lane + 64], ba = b4[lane], bb = b4[lane + 64];
    float4 r0, r1;
    r0.x = (v0.x - mean) * rstd * ga.x + ba.x;
    r0.y = (v0.y - mean) * rstd * ga.y + ba.y;
    r0.z = (v0.z - mean) * rstd * ga.z + ba.z;
    r0.w = (v0.w - mean) * rstd * ga.w + ba.w;
    r1.x = (v1.x - mean) * rstd * gb.x + bb.x;
    r1.y = (v1.y - mean) * rstd * gb.y + bb.y;
    r1.z = (v1.z - mean) * rstd * gb.z + bb.z;
    r1.w = (v1.w - mean) * rstd * gb.w + bb.w;
    if (OUT_BF16) {
        ushort4 o0, o1;
        o0.x = f2bf(r0.x); o0.y = f2bf(r0.y); o0.z = f2bf(r0.z); o0.w = f2bf(r0.w);
        o1.x = f2bf(r1.x); o1.y = f2bf(r1.y); o1.z = f2bf(r1.z); o1.w = f2bf(r1.w);
        ((ushort4*)out)[(size_t)row * 128 + lane] = o0;
        ((ushort4*)out)[(size_t)row * 128 + 64 + lane] = o1;
    } else {
        ((float4*)out)[(size_t)row * 128 + lane] = r0;
        ((float4*)out)[(size_t)row * 128 + 64 + lane] = r1;
    }
}

// ------------- shared GEMM core: 128 x (NT*32) tile, BK=64, XOR-swizzled LDS -------------
// global_load_lds width-16; swizzle permutes each lane's GLOBAL source col-block so that
// LDS[row][cs] = G[row][cs ^ (row&7)] -> conflict-free b128 frag reads without padding.
template <int NT>
__device__ __forceinline__ void gemm_core(const u16* __restrict__ A, const u16* __restrict__ Bt,
                                          int K, v4f (&acc)[4][NT]) {
    constexpr int BN = NT * 32;
    constexpr int NB = NT;   // B 8-row groups per wave
    __shared__ u16 As[128 * 64];
    __shared__ u16 Bs[BN * 64];
    int tid = threadIdx.x;
    int n0 = blockIdx.x * BN, m0 = blockIdx.y * 128;
    int w = tid >> 6, lane = tid & 63;
    int wr = (w >> 1) * 64, wc = (w & 1) * (BN / 2);
    int lr = lane & 15, lq = lane >> 4;
    int r8 = lane >> 3, cb = lane & 7;
    int scol = (cb ^ (r8 & 7)) * 8;

    v4f zero = {0.f, 0.f, 0.f, 0.f};
#pragma unroll
    for (int i = 0; i < 4; i++)
#pragma unroll
        for (int j = 0; j < NT; j++) acc[i][j] = zero;

    const u16* gA[4]; u16* lA[4];
#pragma unroll
    for (int j = 0; j < 4; j++) {
        int row0 = 32 * w + j * 8;
        gA[j] = A + (size_t)(m0 + row0 + r8) * K + scol;
        lA[j] = As + row0 * 64;
    }
    const u16* gB[NB]; u16* lB[NB];
#pragma unroll
    for (int j = 0; j < NB; j++) {
        int row0 = (BN / 4) * w + j * 8;
        gB[j] = Bt + (size_t)(n0 + row0 + r8) * K + scol;
        lB[j] = Bs + row0 * 64;
    }

    for (int k0 = 0; k0 < K; k0 += 64) {
#pragma unroll
        for (int j = 0; j < 4; j++) gl16(gA[j], lA[j]);
#pragma unroll
        for (int j = 0; j < NB; j++) gl16(gB[j], lB[j]);
        __syncthreads();   // vmcnt drain -> tiles ready
#pragma unroll
        for (int kk = 0; kk < 2; kk++) {
            int xb = ((kk * 4 + lq) ^ (lr & 7)) * 8;
            v8bf af[4], bfr[NT];
#pragma unroll
            for (int i = 0; i < 4; i++)
                af[i] = *(const v8bf*)&As[(wr + i * 16 + lr) * 64 + xb];
#pragma unroll
            for (int j = 0; j < NT; j++)
                bfr[j] = *(const v8bf*)&Bs[(wc + j * 16 + lr) * 64 + xb];
#pragma unroll
            for (int mt = 0; mt < 4; mt++)
#pragma unroll
                for (int nt = 0; nt < NT; nt++)
                    acc[mt][nt] = __builtin_amdgcn_mfma_f32_16x16x32_bf16(af[mt], bfr[nt], acc[mt][nt], 0, 0, 0);
        }
        __syncthreads();   // frag reads done before next DMA overwrites
#pragma unroll
        for (int j = 0; j < 4; j++) gA[j] += 64;
#pragma unroll
        for (int j = 0; j < NB; j++) gB[j] += 64;
    }
}

// ---- input projection: fp32 out + bias + sinusoid PE (N=512, BN=64) ----
__global__ __launch_bounds__(256) void gemm_in_kernel(const u16* __restrict__ A,
                                                      const u16* __restrict__ Bt,
                                                      const float* __restrict__ bias,
                                                      float* __restrict__ Out, int K) {
    v4f acc[4][2];
    gemm_core<2>(A, Bt, K, acc);
    int tid = threadIdx.x, w = tid >> 6, lane = tid & 63;
    int lr = lane & 15, lq = lane >> 4;
    int wr = (w >> 1) * 64, wc = (w & 1) * 32;
    int n0 = blockIdx.x * 64, m0 = blockIdx.y * 128;
#pragma unroll
    for (int mt = 0; mt < 4; mt++) {
#pragma unroll
        for (int nt = 0; nt < 2; nt++) {
            int col = n0 + wc + nt * 16 + lr;
            float bcol = bias[col];
            float freq = expf((float)(col & ~1) * (-0.017988946039015984f));
#pragma unroll
            for (int reg = 0; reg < 4; reg++) {
                int row = m0 + wr + mt * 16 + lq * 4 + reg;
                float ang = (float)(row & (S_LEN - 1)) * freq;
                float val = acc[mt][nt][reg] + bcol + ((col & 1) ? cosf(ang) : sinf(ang));
                Out[(size_t)row * DMODEL + col] = val;
            }
        }
    }
}

// ---- fused QKV projection: N=1536 (BN=128); segment block-uniform ----
__global__ __launch_bounds__(256) void gemm_qkv_kernel(const u16* __restrict__ A,
                                                       const u16* __restrict__ Bt,
                                                       const float* __restrict__ bq,
                                                       const float* __restrict__ bk,
                                                       const float* __restrict__ bv,
                                                       u16* __restrict__ Qo,
                                                       u16* __restrict__ Ko,
                                                       u16* __restrict__ Vto, int K) {
    v4f acc[4][4];
    gemm_core<4>(A, Bt, K, acc);
    int tid = threadIdx.x, w = tid >> 6, lane = tid & 63;
    int lr = lane & 15, lq = lane >> 4;
    int wr = (w >> 1) * 64, wc = (w & 1) * 64;
    int n0 = blockIdx.x * 128, m0 = blockIdx.y * 128;
    int seg = n0 >> 9;
#pragma unroll
    for (int mt = 0; mt < 4; mt++) {
#pragma unroll
        for (int nt = 0; nt < 4; nt++) {
            int col = (n0 + wc + nt * 16 + lr) & (DMODEL - 1);
            if (seg == 0) {
                float bcol = bq[col];
#pragma unroll
                for (int reg = 0; reg < 4; reg++) {
                    int row = m0 + wr + mt * 16 + lq * 4 + reg;
                    Qo[(size_t)row * DMODEL + col] = f2bf((acc[mt][nt][reg] + bcol) * QSCALE);
                }
            } else if (seg == 1) {
                float bcol = bk[col];
#pragma unroll
                for (int reg = 0; reg < 4; reg++) {
                    int row = m0 + wr + mt * 16 + lq * 4 + reg;
                    Ko[(size_t)row * DMODEL + col] = f2bf(acc[mt][nt][reg] + bcol);
                }
            } else {
                float bcol = bv[col];
                int row0 = m0 + wr + mt * 16 + lq * 4;
                int bb = row0 >> 10, s0 = row0 & (S_LEN - 1);
                ushort4 o;
                o.x = f2bf(acc[mt][nt][0] + bcol);
                o.y = f2bf(acc[mt][nt][1] + bcol);
                o.z = f2bf(acc[mt][nt][2] + bcol);
                o.w = f2bf(acc[mt][nt][3] + bcol);
                *(ushort4*)(Vto + ((size_t)(bb * DMODEL + col)) * S_LEN + s0) = o;
            }
        }
    }
}

// ---- FFN1: bf16 out + bias + ReLU (N=2048, BN=128) ----
__global__ __launch_bounds__(256) void gemm_relu_kernel(const u16* __restrict__ A,
                                                        const u16* __restrict__ Bt,
                                                        const float* __restrict__ bias,
                                                        u16* __restrict__ Out, int N, int K) {
    v4f acc[4][4];
    gemm_core<4>(A, Bt, K, acc);
    int tid = threadIdx.x, w = tid >> 6, lane = tid & 63;
    int lr = lane & 15, lq = lane >> 4;
    int wr = (w >> 1) * 64, wc = (w & 1) * 64;
    int n0 = blockIdx.x * 128, m0 = blockIdx.y * 128;
#pragma unroll
    for (int mt = 0; mt < 4; mt++) {
#pragma unroll
        for (int nt = 0; nt < 4; nt++) {
            int col = n0 + wc + nt * 16 + lr;
            float bcol = bias[col];
#pragma unroll
            for (int reg = 0; reg < 4; reg++) {
                int row = m0 + wr + mt * 16 + lq * 4 + reg;
                Out[(size_t)row * N + col] = f2bf(fmaxf(acc[mt][nt][reg] + bcol, 0.0f));
            }
        }
    }
}

// ---- O-proj / FFN2: fp32 out + bias + residual in-place (N=512, BN=64) ----
__global__ __launch_bounds__(256) void gemm_res_kernel(const u16* __restrict__ A,
                                                       const u16* __restrict__ Bt,
                                                       const float* __restrict__ bias,
                                                       float* __restrict__ Out, int K) {
    v4f acc[4][2];
    gemm_core<2>(A, Bt, K, acc);
    int tid = threadIdx.x, w = tid >> 6, lane = tid & 63;
    int lr = lane & 15, lq = lane >> 4;
    int wr = (w >> 1) * 64, wc = (w & 1) * 32;
    int n0 = blockIdx.x * 64, m0 = blockIdx.y * 128;
#pragma unroll
    for (int mt = 0; mt < 4; mt++) {
#pragma unroll
        for (int nt = 0; nt < 2; nt++) {
            int col = n0 + wc + nt * 16 + lr;
            float bcol = bias[col];
#pragma unroll
            for (int reg = 0; reg < 4; reg++) {
                int row = m0 + wr + mt * 16 + lq * 4 + reg;
                size_t idx = (size_t)row * DMODEL + col;
                Out[idx] = Out[idx] + acc[mt][nt][reg] + bcol;
            }
        }
    }
}

// ---------------- MFMA flash attention v4: S^T trick ----------------
// QK^T computed operand-swapped (A=K, B=Q) so C-layout gives contiguous key runs:
// P^T[q][key] stored with ds_write_b64, PV A-frags read back as ds_read_b128.
// Q bf16 pre-scaled; K bf16 [B*S][D]; Vt bf16 [(b*512+h*64+d)][s]; fixed softmax max.
#define LDT 72
#define LDP 68
__global__ __launch_bounds__(256) void fattn_kernel(const u16* __restrict__ Qg,
                                                    const u16* __restrict__ Kg,
                                                    const u16* __restrict__ Vtg,
                                                    const float* __restrict__ rb,
                                                    const int* __restrict__ lengths,
                                                    u16* __restrict__ O) {
    int qt = blockIdx.x, h = blockIdx.y, b = blockIdx.z;
    int tid = threadIdx.x, w = tid >> 6, lane = tid & 63;
    int lr = lane & 15, lq = lane >> 4;
    __shared__ u16 Ks[64 * LDT];
    __shared__ u16 Vs[64 * LDT];
    __shared__ u16 Pw[4][32 * LDP];
    __shared__ float rbs[128];
    int len = lengths[b];
    if (tid < 127) rbs[tid] = rb[h * 127 + tid] * 1.4426950408889634f;  // fold log2(e)

    int qw = qt * 128 + w * 32;   // wave's 32 q rows
    v8bf qa[2][2];                // B-operand: rows q = qw + ntq*16 + lr
#pragma unroll
    for (int ntq = 0; ntq < 2; ntq++) {
        size_t qrow = ((size_t)(b * S_LEN + qw + ntq * 16 + lr)) * DMODEL + h * DK;
        qa[ntq][0] = *(const v8bf*)(Qg + qrow + lq * 8);
        qa[ntq][1] = *(const v8bf*)(Qg + qrow + 32 + lq * 8);
    }

    v4f zero = {0.f, 0.f, 0.f, 0.f};
    v4f Oacc[2][4];
#pragma unroll
    for (int mt = 0; mt < 2; mt++)
#pragma unroll
        for (int nt = 0; nt < 4; nt++) Oacc[mt][nt] = zero;
    float lsum[2] = {0.f, 0.f};

    const u16* Kbase = Kg + ((size_t)b * S_LEN) * DMODEL + h * DK;
    const u16* Vbase = Vtg + ((size_t)(b * DMODEL + h * DK)) * S_LEN;
    u16* P = Pw[w];
    int sr = tid >> 3, sc = (tid & 7) * 8;

    for (int kb0 = 0; kb0 < len; kb0 += 64) {
        __syncthreads();   // prev-iter LDS reads done (also covers rbs on iter 0)
#pragma unroll
        for (int j = 0; j < 2; j++) {
            int rr = sr + j * 32;
            *(v8bf*)&Ks[rr * LDT + sc] = *(const v8bf*)(Kbase + (size_t)(kb0 + rr) * DMODEL + sc);
            *(v8bf*)&Vs[rr * LDT + sc] = *(const v8bf*)(Vbase + (size_t)rr * S_LEN + kb0 + sc);
        }
        __syncthreads();

        // A-operand K fragments: m = key = mtk*16 + lq*4 + reg (C rows), k = d
        v8bf kf[4][2];
#pragma unroll
        for (int mtk = 0; mtk < 4; mtk++) {
            kf[mtk][0] = *(const v8bf*)&Ks[(mtk * 16 + lr) * LDT + lq * 8];
            kf[mtk][1] = *(const v8bf*)&Ks[(mtk * 16 + lr) * LDT + 32 + lq * 8];
        }

        // S^T = K @ Q^T : lane holds key = kb0+mtk*16+lq*4+r, q = qw+ntq*16+lr
        v4f S[4][2];
#pragma unroll
        for (int mtk = 0; mtk < 4; mtk++)
#pragma unroll
            for (int ntq = 0; ntq < 2; ntq++) {
                v4f s = __builtin_amdgcn_mfma_f32_16x16x32_bf16(kf[mtk][0], qa[ntq][0], zero, 0, 0, 0);
                S[mtk][ntq] = __builtin_amdgcn_mfma_f32_16x16x32_bf16(kf[mtk][1], qa[ntq][1], s, 0, 0, 0);
            }

        bool edge = (kb0 + 64 > len);
        int dmin = qw - (kb0 + 63), dmax = qw + 31 - kb0;
        bool perel = !(dmax <= -63 || dmin >= 63);
        float bconst = (dmax <= -63) ? rbs[0] : rbs[126];
#pragma unroll
        for (int mtk = 0; mtk < 4; mtk++) {
#pragma unroll
            for (int ntq = 0; ntq < 2; ntq++) {
                int q = qw + ntq * 16 + lr;
                ushort4 pk;
#pragma unroll
                for (int r = 0; r < 4; r++) {
                    int key = kb0 + mtk * 16 + lq * 4 + r;
                    float s = S[mtk][ntq][r];
                    if (perel) {
                        int d = q - key;
                        d = d < -63 ? -63 : (d > 63 ? 63 : d);
                        s += rbs[d + 63];
                    } else {
                        s += bconst;
                    }
                    float p = exp2f(s);
                    if (edge && key >= len) p = 0.f;
                    lsum[ntq] += p;
                    ((u16*)&pk)[r] = f2bf(p);
                }
                // P^T[q-local][key-local]: 4 contiguous keys -> one b64 write
                *(ushort4*)&P[(ntq * 16 + lr) * LDP + mtk * 16 + lq * 4] = pk;
            }
        }

        // O += P @ V : A = P^T rows (m=q), B = V (n=d); b128 reads all around
        v8bf vb[4][2];
#pragma unroll
        for (int ntd = 0; ntd < 4; ntd++) {
            vb[ntd][0] = *(const v8bf*)&Vs[(ntd * 16 + lr) * LDT + lq * 8];
            vb[ntd][1] = *(const v8bf*)&Vs[(ntd * 16 + lr) * LDT + 32 + lq * 8];
        }
#pragma unroll
        for (int mtq = 0; mtq < 2; mtq++) {
            v8bf pa0 = *(const v8bf*)&P[(mtq * 16 + lr) * LDP + lq * 8];
            v8bf pa1 = *(const v8bf*)&P[(mtq * 16 + lr) * LDP + 32 + lq * 8];
#pragma unroll
            for (int ntd = 0; ntd < 4; ntd++) {
                Oacc[mtq][ntd] = __builtin_amdgcn_mfma_f32_16x16x32_bf16(pa0, vb[ntd][0], Oacc[mtq][ntd], 0, 0, 0);
                Oacc[mtq][ntd] = __builtin_amdgcn_mfma_f32_16x16x32_bf16(pa1, vb[ntd][1], Oacc[mtq][ntd], 0, 0, 0);
            }
        }
    }

    // reduce row sums across quads (lane lr then holds total for q = tile_base + lr)
    float lsumR[2];
#pragma unroll
    for (int ntq = 0; ntq < 2; ntq++) {
        float s = lsum[ntq];
        s += __shfl_xor(s, 16);
        s += __shfl_xor(s, 32);
        lsumR[ntq] = s;
    }
#pragma unroll
    for (int mtq = 0; mtq < 2; mtq++) {
        float inv[4];
#pragma unroll
        for (int r = 0; r < 4; r++)
            inv[r] = 1.0f / __shfl(lsumR[mtq], lq * 4 + r);
        size_t obase = ((size_t)(b * S_LEN + qw + mtq * 16)) * DMODEL + h * DK;
#pragma unroll
        for (int ntd = 0; ntd < 4; ntd++)
#pragma unroll
            for (int r = 0; r < 4; r++)
                O[obase + (size_t)(lq * 4 + r) * DMODEL + ntd * 16 + lr] = f2bf(Oacc[mtq][ntd][r] * inv[r]);
    }
}

extern "C" void kernel_launch(void* const* d_in, const int* in_sizes, int n_in,
                              void* d_out, int out_size, void* d_ws, size_t ws_size,
                              hipStream_t stream) {
    const float* inputs   = (const float*)d_in[0];
    const int*   lengths  = (const int*)d_in[1];
    const float* W_in     = (const float*)d_in[2];
    const float* b_in     = (const float*)d_in[3];
    const float* Wq       = (const float*)d_in[4];
    const float* bq       = (const float*)d_in[5];
    const float* Wk       = (const float*)d_in[6];
    const float* bk       = (const float*)d_in[7];
    const float* Wv       = (const float*)d_in[8];
    const float* bv       = (const float*)d_in[9];
    const float* Wo       = (const float*)d_in[10];
    const float* bo       = (const float*)d_in[11];
    const float* rel_bias = (const float*)d_in[12];
    const float* W1       = (const float*)d_in[13];
    const float* b1       = (const float*)d_in[14];
    const float* W2       = (const float*)d_in[15];
    const float* b2       = (const float*)d_in[16];
    const float* g1       = (const float*)d_in[17];
    const float* be1      = (const float*)d_in[18];
    const float* g2       = (const float*)d_in[19];
    const float* be2      = (const float*)d_in[20];
    const float* gf       = (const float*)d_in[21];
    const float* bef      = (const float*)d_in[22];

    // ---- workspace layout ----
    char* ws = (char*)d_ws;
    float* xbuf = (float*)ws;          ws += (size_t)MROWS * DMODEL * 4;   // residual fp32
    u16* hbuf   = (u16*)ws;            ws += (size_t)MROWS * DMODEL * 2;   // LN output bf16
    u16* aobuf  = (u16*)ws;            ws += (size_t)MROWS * DMODEL * 2;   // attn output bf16
    u16* qbf    = (u16*)ws;                                                // union region (48MB):
    u16* kbf    = qbf + (size_t)MROWS * DMODEL;                            //  q/k/vt bf16 (24MB)
    u16* vtbf   = kbf + (size_t)MROWS * DMODEL;                            //  OR FFN mid (32MB)
    u16* tbuf   = qbf;                 ws += (size_t)MROWS * DMODEL * 4 * 3;
    u16* inbf   = (u16*)ws;            ws += (size_t)MROWS * IN_DIM * 2;   // bf16 inputs
    u16* wt_in  = (u16*)ws;            ws += (size_t)DMODEL * IN_DIM * 2;
    u16 *qkvw[2], *wto[2], *wt1[2], *wt2[2];
    for (int l = 0; l < 2; l++) { qkvw[l] = (u16*)ws; ws += (size_t)3 * DMODEL * DMODEL * 2; }
    for (int l = 0; l < 2; l++) { wto[l] = (u16*)ws; ws += (size_t)DMODEL * DMODEL * 2; }
    for (int l = 0; l < 2; l++) { wt1[l] = (u16*)ws; ws += (size_t)FF_DIM * DMODEL * 2; }
    for (int l = 0; l < 2; l++) { wt2[l] = (u16*)ws; ws += (size_t)DMODEL * FF_DIM * 2; }

    TArgs ta;
    int ti = 0;
    ta.d[ti++] = {W_in, wt_in, IN_DIM, DMODEL};
    for (int l = 0; l < 2; l++) {
        ta.d[ti++] = {Wq + (size_t)l * DMODEL * DMODEL, qkvw[l], DMODEL, DMODEL};
        ta.d[ti++] = {Wk + (size_t)l * DMODEL * DMODEL, qkvw[l] + (size_t)DMODEL * DMODEL, DMODEL, DMODEL};
        ta.d[ti++] = {Wv + (size_t)l * DMODEL * DMODEL, qkvw[l] + (size_t)2 * DMODEL * DMODEL, DMODEL, DMODEL};
        ta.d[ti++] = {Wo + (size_t)l * DMODEL * DMODEL, wto[l], DMODEL, DMODEL};
        ta.d[ti++] = {W1 + (size_t)l * DMODEL * FF_DIM, wt1[l], DMODEL, FF_DIM};
        ta.d[ti++] = {W2 + (size_t)l * FF_DIM * DMODEL, wt2[l], FF_DIM, DMODEL};
    }

    conv_bf16_kernel<<<dim3((MROWS * IN_DIM / 4 + 255) / 256), 256, 0, stream>>>(
        inputs, inbf, MROWS * IN_DIM / 4);
    transpose_conv_kernel<<<dim3(64, 64, 13), dim3(32, 8), 0, stream>>>(ta);

    gemm_in_kernel<<<dim3(DMODEL / 64, MROWS / 128), 256, 0, stream>>>(
        inbf, wt_in, b_in, xbuf, IN_DIM);

    for (int l = 0; l < 2; l++) {
        ln_kernel<true><<<MROWS / 4, 256, 0, stream>>>(xbuf, g1 + l * DMODEL, be1 + l * DMODEL, hbuf);
        gemm_qkv_kernel<<<dim3(3 * DMODEL / 128, MROWS / 128), 256, 0, stream>>>(
            hbuf, qkvw[l], bq + l * DMODEL, bk + l * DMODEL, bv + l * DMODEL,
            qbf, kbf, vtbf, DMODEL);
        fattn_kernel<<<dim3(S_LEN / 128, NHEAD, B_SZ), 256, 0, stream>>>(
            qbf, kbf, vtbf, rel_bias + (size_t)l * NHEAD * 127, lengths, aobuf);
        gemm_res_kernel<<<dim3(DMODEL / 64, MROWS / 128), 256, 0, stream>>>(
            aobuf, wto[l], bo + l * DMODEL, xbuf, DMODEL);
        ln_kernel<true><<<MROWS / 4, 256, 0, stream>>>(xbuf, g2 + l * DMODEL, be2 + l * DMODEL, hbuf);
        gemm_relu_kernel<<<dim3(FF_DIM / 128, MROWS / 128), 256, 0, stream>>>(
            hbuf, wt1[l], b1 + l * FF_DIM, tbuf, FF_DIM, DMODEL);
        gemm_res_kernel<<<dim3(DMODEL / 64, MROWS / 128), 256, 0, stream>>>(
            tbuf, wt2[l], b2 + l * DMODEL, xbuf, FF_DIM);
    }
    ln_kernel<false><<<MROWS / 4, 256, 0, stream>>>(xbuf, gf, bef, d_out);
}